// Round 17
// baseline (2200.665 us; speedup 1.0000x reference)
//
#include <hip/hip_runtime.h>
#include <math.h>

#define LNUM 6
#define HNUM 8
#define DMODEL 512
#define DHEAD 64
#define MFEAT 256
#define BATCH 8
#define SEQ 2048
#define TOK (BATCH*SEQ)
#define BHN (BATCH*HNUM)
#define DFF 2048
#define EPSF 1e-4f
#define LN_EPS 1e-5f
#define DNRM 0.35355339059327373f
#define SMF 0.0625f

typedef unsigned short u16;
typedef __attribute__((ext_vector_type(8))) short bf16x8;
typedef __attribute__((ext_vector_type(4))) float f32x4;
#define MFMA16(a,b,c) __builtin_amdgcn_mfma_f32_16x16x32_bf16(a,b,c,0,0,0)

// async global->LDS, 16B per lane; LDS dest = wave-uniform base + lane*16
#define GLOAD16(g,l) __builtin_amdgcn_global_load_lds( \
    (const __attribute__((address_space(1))) void*)(g), \
    (__attribute__((address_space(3))) void*)(l), 16, 0, 0)

__device__ __forceinline__ u16 f2bf(float f){
  unsigned int u = __float_as_uint(f);
  u = (u + 0x7fffu + ((u >> 16) & 1u)) >> 16;
  return (u16)u;
}
__device__ __forceinline__ float bf2f(u16 s){
  return __uint_as_float(((unsigned int)s) << 16);
}
__device__ __forceinline__ u16 f2h(float f){
  _Float16 h = (_Float16)f;
  return *(u16*)&h;
}
__device__ __forceinline__ float h2f(u16 s){
  _Float16 h = *(_Float16*)&s;
  return (float)h;
}
__device__ __forceinline__ void atomicMaxF(float* addr, float val){
  if(val >= 0.f) atomicMax((int*)addr, __float_as_int(val));
  else           atomicMin((unsigned int*)addr, __float_as_uint(val));
}
// gelu tanh-approx: z * sigmoid(2*(c1 z + c2 z^3))
__device__ __forceinline__ float fast_gelu(float z){
  float g2 = z*(1.5957691216f + 0.07135481628f*z*z);
  return z / (1.0f + __expf(-g2));
}

// ---------------- x = x + sinusoidal PE ----------------
__global__ void k_addpe(const float* __restrict__ x, float* __restrict__ xo){
  int idx = blockIdx.x*256 + threadIdx.x;
  int d = idx & (DMODEL-1);
  int n = (idx >> 9) & (SEQ-1);
  int j = d >> 1;
  float freq = expf((float)(2*j) * (-9.210340371976184f / (float)DMODEL));
  float ang = (float)n * freq;
  float pe = (d & 1) ? cosf(ang) : sinf(ang);
  xo[idx] = x[idx] + pe;
}

// ---------------- LayerNorm (512) -> bf16 ----------------
__global__ void k_ln(const float* __restrict__ x, const float* __restrict__ g,
                     const float* __restrict__ bv, u16* __restrict__ out){
  __shared__ float sred[8];
  int t = blockIdx.x, tid = threadIdx.x;
  const float2 v = ((const float2*)(x + (size_t)t*DMODEL))[tid];
  float s = v.x + v.y;
  #pragma unroll
  for(int o=32;o;o>>=1) s += __shfl_down(s,o);
  if((tid&63)==0) sred[tid>>6] = s;
  __syncthreads();
  if(tid==0) sred[4] = (sred[0]+sred[1]+sred[2]+sred[3]) * (1.0f/DMODEL);
  __syncthreads();
  float mu = sred[4];
  float dx = v.x - mu, dy = v.y - mu;
  float s2 = dx*dx + dy*dy;
  #pragma unroll
  for(int o=32;o;o>>=1) s2 += __shfl_down(s2,o);
  if((tid&63)==0) sred[tid>>6] = s2;
  __syncthreads();
  if(tid==0) sred[5] = rsqrtf((sred[0]+sred[1]+sred[2]+sred[3])*(1.0f/DMODEL) + LN_EPS);
  __syncthreads();
  float rs = sred[5];
  const float2 gg = ((const float2*)g)[tid];
  const float2 bb = ((const float2*)bv)[tid];
  ushort2 o2; o2.x = f2bf(dx*rs*gg.x + bb.x); o2.y = f2bf(dy*rs*gg.y + bb.y);
  ((ushort2*)(out + (size_t)t*DMODEL))[tid] = o2;
}

__global__ void k_pcvt(const float* __restrict__ p, u16* __restrict__ pb){
  int i = blockIdx.x*256 + threadIdx.x;
  pb[i] = f2bf(p[i]);
}

// ---------------- all weight transposes + kmax init in ONE dispatch ----------------
__global__ void k_wcvt_all(const float* __restrict__ wq, const float* __restrict__ wk,
                           const float* __restrict__ wv, const float* __restrict__ wo,
                           const float* __restrict__ w1, const float* __restrict__ w2,
                           u16* __restrict__ wqT, u16* __restrict__ wkT,
                           u16* __restrict__ wvT, u16* __restrict__ woT,
                           u16* __restrict__ w1T, u16* __restrict__ w2T,
                           float* __restrict__ kmax){
  int bid = blockIdx.x;
  if(bid >= 768){
    int i = (bid-768)*256 + threadIdx.x;
    if(i < BHN) kmax[i] = -INFINITY;
    return;
  }
  const float* src; u16* dst; int K, N, bx, by;
  if(bid < 256){
    int which = bid >> 6, sub = bid & 63;
    src = which==0 ? wq : which==1 ? wk : which==2 ? wv : wo;
    dst = which==0 ? wqT : which==1 ? wkT : which==2 ? wvT : woT;
    K = 512; N = 512; bx = sub & 7; by = sub >> 3;
  } else if(bid < 512){
    int sub = bid - 256; src = w1; dst = w1T; K = 512; N = 2048; bx = sub & 31; by = sub >> 5;
  } else {
    int sub = bid - 512; src = w2; dst = w2T; K = 2048; N = 512; bx = sub & 7; by = sub >> 3;
  }
  __shared__ float sm[64][65];
  int kt = by*64, nt = bx*64;
  int t = threadIdx.x, c = t & 63, r4 = t >> 6;
  #pragma unroll
  for(int i=0;i<16;i++){
    int kl = i*4 + r4;
    sm[kl][c] = src[(size_t)(kt+kl)*N + nt + c];
  }
  __syncthreads();
  #pragma unroll
  for(int i=0;i<16;i++){
    int nl = i*4 + r4;
    dst[(size_t)(nt+nl)*K + kt + c] = f2bf(sm[c][nl]);
  }
}

// ---------------- MFMA GEMM, 128x128, BK=32, depth-2, counted vmcnt, 128-reg cap ----------------
template<int EPI>
__global__ __launch_bounds__(256,4)
void k_mm(const u16* __restrict__ A, const u16* __restrict__ Bt,
          const float* __restrict__ bias, void* __restrict__ Cv,
          int Nc, int K){
  __shared__ u16 As[2][128*32];
  __shared__ u16 Bs[2][128*32];
  int tid = threadIdx.x;
  int w = tid >> 6, lane = tid & 63;
  int wr = w >> 1, wc = w & 1;
  int hi = lane >> 4, li = lane & 15;
  int row0 = blockIdx.y*128, col0 = blockIdx.x*128;
  int lr = lane >> 2;
  int cs = (lane & 3) ^ ((lane >> 3) & 3);
  const u16* gA = A  + (size_t)(row0 + w*16 + lr)*K + cs*8;
  const u16* gB = Bt + (size_t)(col0 + w*16 + lr)*K + cs*8;
  int rb = li*32 + ((hi ^ ((li>>1)&3))<<3);
  f32x4 acc[4][4] = {};

#define STAGE_MM(b,k0) { \
    GLOAD16(gA + (k0),                &As[b][(w*16)*32]);      \
    GLOAD16(gA + (size_t)64*K + (k0), &As[b][(64+w*16)*32]);   \
    GLOAD16(gB + (k0),                &Bs[b][(w*16)*32]);      \
    GLOAD16(gB + (size_t)64*K + (k0), &Bs[b][(64+w*16)*32]); }

  int nk = K >> 5;
  STAGE_MM(0, 0)
  STAGE_MM(1, 32)
  for(int t=0; t<nk; ++t){
    __builtin_amdgcn_sched_barrier(0);
    if(t+1 < nk){ asm volatile("s_waitcnt vmcnt(4)"); }
    else        { asm volatile("s_waitcnt vmcnt(0)"); }
    __builtin_amdgcn_s_barrier();
    __builtin_amdgcn_sched_barrier(0);
    const u16* pa = &As[t&1][0];
    const u16* pb = &Bs[t&1][0];
    bf16x8 bfr[4];
    #pragma unroll
    for(int q=0;q<4;q++) bfr[q] = *(const bf16x8*)&pb[rb + wc*2048 + q*512];
    __builtin_amdgcn_s_setprio(1);
    #pragma unroll
    for(int i2=0;i2<4;i2++){
      bf16x8 a = *(const bf16x8*)&pa[rb + wr*2048 + i2*512];
      #pragma unroll
      for(int j2=0;j2<4;j2++)
        acc[i2][j2] = MFMA16(a, bfr[j2], acc[i2][j2]);
    }
    __builtin_amdgcn_s_setprio(0);
    __builtin_amdgcn_sched_barrier(0);
    __builtin_amdgcn_s_barrier();
    __builtin_amdgcn_sched_barrier(0);
    if(t+2 < nk){ STAGE_MM(t&1, (size_t)(t+2)*32) }
  }
#undef STAGE_MM

  #pragma unroll
  for(int i2=0;i2<4;i2++){
    #pragma unroll
    for(int j2=0;j2<4;j2++){
      int col = col0 + wc*64 + j2*16 + li;
      float bcol = (EPI==2 || EPI==3) ? bias[col] : 0.f;
      if constexpr (EPI==4){
        int nb = row0 + wr*64 + i2*16 + hi*4;
        int b = nb >> 11, n = nb & (SEQ-1);
        int h = col >> 6, dh = col & 63;
        ushort4 pk;
        pk.x = f2bf(acc[i2][j2][0]); pk.y = f2bf(acc[i2][j2][1]);
        pk.z = f2bf(acc[i2][j2][2]); pk.w = f2bf(acc[i2][j2][3]);
        *(ushort4*)((u16*)Cv + (((size_t)(b*HNUM+h)*DHEAD + dh)*SEQ + n)) = pk;
      } else {
        #pragma unroll
        for(int r=0;r<4;r++){
          int row = row0 + wr*64 + i2*16 + hi*4 + r;
          float v = acc[i2][j2][r];
          if constexpr (EPI==1){
            int b = row >> 11, n = row & (SEQ-1);
            int h = col >> 6, dh = col & 63;
            ((u16*)Cv)[((size_t)(b*HNUM+h)*SEQ + n)*DHEAD + dh] = f2bf(v);
          } else if constexpr (EPI==2){
            ((float*)Cv)[(size_t)row*Nc + col] += v + bcol;
          } else {
            ((u16*)Cv)[(size_t)row*Nc + col] = f2bf(fast_gelu(v + bcol));
          }
        }
      }
    }
  }
}

// ---------------- MFMA GEMM, 256x128 tile, BK=64, 3-buffer phase-split ----------------
template<int EPI>
__global__ __launch_bounds__(512)
void k_mm8(const u16* __restrict__ A, const u16* __restrict__ Bt,
           const float* __restrict__ bias, void* __restrict__ Cv,
           int Nc, int K){
  __shared__ u16 Ab[3][256*64];
  __shared__ u16 Bb[3][128*64];
  int tid = threadIdx.x;
  int w = tid >> 6, lane = tid & 63;
  int wr = w >> 1, wc = w & 1;
  int hi = lane >> 4, li = lane & 15;
  int row0 = blockIdx.y*256, col0 = blockIdx.x*128;
  int lr = lane >> 3;
  int lc = (lane & 7) ^ lr;
  const u16* gA = A  + (size_t)(row0 + w*8 + lr)*K + lc*8;
  const u16* gB = Bt + (size_t)(col0 + w*8 + lr)*K + lc*8;
  f32x4 acc[4][4] = {};

#define STG8(buf,k0) { \
    GLOAD16(gA + (k0),                  &Ab[buf][w*512]);          \
    GLOAD16(gA + (size_t)64*K  + (k0),  &Ab[buf][4096  + w*512]);  \
    GLOAD16(gA + (size_t)128*K + (k0),  &Ab[buf][8192  + w*512]);  \
    GLOAD16(gA + (size_t)192*K + (k0),  &Ab[buf][12288 + w*512]);  \
    GLOAD16(gB + (k0),                  &Bb[buf][w*512]);          \
    GLOAD16(gB + (size_t)64*K  + (k0),  &Bb[buf][4096  + w*512]); }

  int nk = K >> 6;
  STG8(0, 0)
  STG8(1, 64)
  for(int t=0; t<nk; ++t){
    int buf = t % 3;
    int nbuf = (t+2) % 3;
    size_t nk0 = (size_t)(t+2)*64;
    __builtin_amdgcn_sched_barrier(0);
    if(t+1 < nk){ asm volatile("s_waitcnt vmcnt(6)"); }
    else        { asm volatile("s_waitcnt vmcnt(0)"); }
    __builtin_amdgcn_s_barrier();
    __builtin_amdgcn_sched_barrier(0);
    const u16* pa = &Ab[buf][0];
    const u16* pb = &Bb[buf][0];
    bf16x8 bfr[2][4], af[2][2];
    #pragma unroll
    for(int kk=0;kk<2;kk++){
      int kc = kk*4 + hi;
      #pragma unroll
      for(int j=0;j<4;j++){
        int bc = wc*64 + j*16 + li;
        bfr[kk][j] = *(const bf16x8*)&pb[bc*64 + ((kc ^ (bc&7))<<3)];
      }
      #pragma unroll
      for(int q=0;q<2;q++){
        int ar = wr*64 + q*16 + li;
        af[kk][q] = *(const bf16x8*)&pa[ar*64 + ((kc ^ (ar&7))<<3)];
      }
    }
    if(t+2 < nk){
      GLOAD16(gA + nk0,                  &Ab[nbuf][w*512]);
      GLOAD16(gA + (size_t)64*K  + nk0,  &Ab[nbuf][4096  + w*512]);
      GLOAD16(gA + (size_t)128*K + nk0,  &Ab[nbuf][8192  + w*512]);
    }
    __builtin_amdgcn_s_setprio(1);
    #pragma unroll
    for(int kk=0;kk<2;kk++)
      #pragma unroll
      for(int q=0;q<2;q++)
        #pragma unroll
        for(int j=0;j<4;j++)
          acc[q][j] = MFMA16(af[kk][q], bfr[kk][j], acc[q][j]);
    __builtin_amdgcn_s_setprio(0);
    __builtin_amdgcn_s_barrier();
    bf16x8 af2[2][2];
    #pragma unroll
    for(int kk=0;kk<2;kk++){
      int kc = kk*4 + hi;
      #pragma unroll
      for(int q=0;q<2;q++){
        int ar = wr*64 + (q+2)*16 + li;
        af2[kk][q] = *(const bf16x8*)&pa[ar*64 + ((kc ^ (ar&7))<<3)];
      }
    }
    if(t+2 < nk){
      GLOAD16(gA + (size_t)192*K + nk0,  &Ab[nbuf][12288 + w*512]);
      GLOAD16(gB + nk0,                  &Bb[nbuf][w*512]);
      GLOAD16(gB + (size_t)64*K  + nk0,  &Bb[nbuf][4096  + w*512]);
    }
    __builtin_amdgcn_s_setprio(1);
    #pragma unroll
    for(int kk=0;kk<2;kk++)
      #pragma unroll
      for(int q=0;q<2;q++)
        #pragma unroll
        for(int j=0;j<4;j++)
          acc[q+2][j] = MFMA16(af2[kk][q], bfr[kk][j], acc[q+2][j]);
    __builtin_amdgcn_s_setprio(0);
    __builtin_amdgcn_s_barrier();
  }
#undef STG8

  #pragma unroll
  for(int i2=0;i2<4;i2++){
    #pragma unroll
    for(int j2=0;j2<4;j2++){
      int col = col0 + wc*64 + j2*16 + li;
      float bcol = (EPI==2 || EPI==3) ? bias[col] : 0.f;
      if constexpr (EPI==4){
        int nb = row0 + wr*64 + i2*16 + hi*4;
        int b = nb >> 11, n = nb & (SEQ-1);
        int h = col >> 6, dh = col & 63;
        ushort4 pk;
        pk.x = f2bf(acc[i2][j2][0]); pk.y = f2bf(acc[i2][j2][1]);
        pk.z = f2bf(acc[i2][j2][2]); pk.w = f2bf(acc[i2][j2][3]);
        *(ushort4*)((u16*)Cv + (((size_t)(b*HNUM+h)*DHEAD + dh)*SEQ + n)) = pk;
      } else {
        #pragma unroll
        for(int r=0;r<4;r++){
          int row = row0 + wr*64 + i2*16 + hi*4 + r;
          float v = acc[i2][j2][r];
          if constexpr (EPI==1){
            int b = row >> 11, n = row & (SEQ-1);
            int h = col >> 6, dh = col & 63;
            ((u16*)Cv)[((size_t)(b*HNUM+h)*SEQ + n)*DHEAD + dh] = f2bf(v);
          } else if constexpr (EPI==2){
            ((float*)Cv)[(size_t)row*Nc + col] += v + bcol;
          } else {
            ((u16*)Cv)[(size_t)row*Nc + col] = f2bf(fast_gelu(v + bcol));
          }
        }
      }
    }
  }
}

// ---------------- K u-pass: 128 rows/block, writes u_t - diag (f16) + global max ----------------
__global__ __launch_bounds__(256)
void k_ku(const u16* __restrict__ xg, const u16* __restrict__ pjb,
          u16* __restrict__ outp, float* __restrict__ kmax){
  __shared__ u16 pj[256*64];
  __shared__ u16 xs[128*64];
  __shared__ float dgs[128];
  __shared__ float wred[4];
  int tid = threadIdx.x, w = tid >> 6, lane = tid & 63;
  int hi = lane >> 4, li = lane & 15;
  int r0 = blockIdx.x * 128;
  int bh = r0 >> 11;
  int nbase = r0 & (SEQ-1);
  #pragma unroll
  for(int i=0;i<8;i++){
    int idx = i*256 + tid;
    int m = idx >> 3, c = idx & 7;
    bf16x8 v = *(const bf16x8*)(pjb + m*64 + c*8);
    *(bf16x8*)&pj[m*64 + ((c ^ (m&7))<<3)] = v;
  }
  #pragma unroll
  for(int i=0;i<4;i++){
    int idx = i*256 + tid;
    int m = idx >> 3, c = idx & 7;
    bf16x8 v = *(const bf16x8*)(xg + (size_t)(r0+m)*64 + c*8);
    *(bf16x8*)&xs[m*64 + ((c ^ (m&7))<<3)] = v;
    float s = 0.f;
    #pragma unroll
    for(int j=0;j<8;j++){ float t = bf2f((u16)v[j]); s += t*t; }
    s += __shfl_xor(s,1); s += __shfl_xor(s,2); s += __shfl_xor(s,4);
    if((tid&7)==0) dgs[m] = 0.5f*DNRM*DNRM*s;
  }
  __syncthreads();
  bf16x8 bfr[2][4];
  #pragma unroll
  for(int ks=0;ks<2;ks++){
    int kc = ks*4 + hi;
    #pragma unroll
    for(int t=0;t<4;t++){
      int bc = w*64 + t*16 + li;
      bfr[ks][t] = *(const bf16x8*)&pj[bc*64 + ((kc ^ (bc&7))<<3)];
    }
  }
  float mx = -1e30f;
  #pragma unroll
  for(int i8=0;i8<8;i8++){
    f32x4 acc[4] = {};
    #pragma unroll
    for(int ks=0;ks<2;ks++){
      int kc = ks*4 + hi;
      int ar = i8*16 + li;
      bf16x8 af = *(const bf16x8*)&xs[ar*64 + ((kc ^ (ar&7))<<3)];
      #pragma unroll
      for(int j2=0;j2<4;j2++)
        acc[j2] = MFMA16(af, bfr[ks][j2], acc[j2]);
    }
    #pragma unroll
    for(int j2=0;j2<4;j2++){
      int col = w*64 + j2*16 + li;
      ushort4 pk;
      #pragma unroll
      for(int r=0;r<4;r++){
        int rl = i8*16 + hi*4 + r;
        mx = fmaxf(mx, acc[j2][r]);
        ((u16*)&pk)[r] = f2h(acc[j2][r]*DNRM - dgs[rl]);
      }
      *(ushort4*)(outp + ((size_t)(bh*MFEAT + col)*SEQ + nbase + i8*16 + hi*4)) = pk;
    }
  }
  #pragma unroll
  for(int o=32;o;o>>=1) mx = fmaxf(mx, __shfl_xor(mx,o));
  if(lane==0) wred[w] = mx;
  __syncthreads();
  if(tid==0){
    float m2 = fmaxf(fmaxf(wred[0],wred[1]), fmaxf(wred[2],wred[3]));
    atomicMaxF(&kmax[bh], m2*DNRM);
  }
}

// ---------------- K exp pass: in-place featb (f16 u-diag -> bf16 kp) + direct ksum ----------------
// block owns 8 complete m-rows; thread covers 64 n; no atomics.
__global__ __launch_bounds__(256)
void k_kexp(u16* __restrict__ featb, const float* __restrict__ kmax,
            float* __restrict__ ksum){
  int row = blockIdx.x*8 + (threadIdx.x >> 5);   // bh*MFEAT + m
  int l32 = threadIdx.x & 31;
  float km = kmax[row >> 8];
  u16* p = featb + (size_t)row*SEQ + l32*64;
  float s = 0.f;
  #pragma unroll
  for(int i=0;i<8;i++){
    bf16x8 v = *(bf16x8*)(p + i*8);
    bf16x8 o;
    #pragma unroll
    for(int j=0;j<8;j++){
      float x = h2f((u16)v[j]);
      u16 eb = f2bf(SMF*(__expf(x - km) + EPSF));
      o[j] = (short)eb;
      s += bf2f(eb);
    }
    *(bf16x8*)(p + i*8) = o;
  }
  s += __shfl_xor(s,1); s += __shfl_xor(s,2); s += __shfl_xor(s,4);
  s += __shfl_xor(s,8); s += __shfl_xor(s,16);
  if(l32 == 0) ksum[row] = s;
}

// ---------------- fused Q-feature + PV, 512 threads / 64 rows per block ----------------
__global__ __launch_bounds__(512)
void k_feato(const u16* __restrict__ xg, const u16* __restrict__ pjb,
             const u16* __restrict__ ctxt, const float* __restrict__ ksum,
             u16* __restrict__ o){
  __shared__ u16 smA[16384];
  __shared__ u16 smX[4096];
  __shared__ u16 smQ[64*264];
  __shared__ float dgs[64];
  __shared__ float wred[2][4][32];
  __shared__ float wden[2][4][32];
  __shared__ float ksl[256];
  __shared__ float denl[64];
  int tid = threadIdx.x, w = tid >> 6, lane = tid & 63;
  int hi = lane >> 4, li = lane & 15;
  int g = w >> 2, wq = w & 3;
  int r0 = blockIdx.x * 64;
  int bh = r0 >> 11;
  int b = bh >> 3, h = bh & 7;
  #pragma unroll
  for(int i=0;i<4;i++){
    int idx = i*512 + tid;
    int m = idx >> 3, c = idx & 7;
    bf16x8 v = *(const bf16x8*)(pjb + m*64 + c*8);
    *(bf16x8*)&smA[m*64 + ((c ^ (m&7))<<3)] = v;
  }
  {
    int m = tid >> 3, c = tid & 7;
    bf16x8 v = *(const bf16x8*)(xg + (size_t)(r0+m)*64 + c*8);
    *(bf16x8*)&smX[m*64 + ((c ^ (m&7))<<3)] = v;
    float s = 0.f;
    #pragma unroll
    for(int j=0;j<8;j++){ float t = bf2f((u16)v[j]); s += t*t; }
    s += __shfl_xor(s,1); s += __shfl_xor(s,2); s += __shfl_xor(s,4);
    if((tid&7)==0) dgs[m] = 0.5f*DNRM*DNRM*s;
  }
  if(tid < 256) ksl[tid] = ksum[bh*MFEAT + tid];
  __syncthreads();
  f32x4 acc[2][4] = {};
  #pragma unroll
  for(int ks=0;ks<2;ks++){
    bf16x8 af[2], bfr[4];
    int kc = ks*4 + hi;
    #pragma unroll
    for(int t=0;t<2;t++){
      int ar = g*32 + t*16 + li;
      af[t] = *(const bf16x8*)&smX[ar*64 + ((kc ^ (ar&7))<<3)];
    }
    #pragma unroll
    for(int t=0;t<4;t++){
      int bc = wq*64 + t*16 + li;
      bfr[t] = *(const bf16x8*)&smA[bc*64 + ((kc ^ (bc&7))<<3)];
    }
    #pragma unroll
    for(int i2=0;i2<2;i2++)
      #pragma unroll
      for(int j2=0;j2<4;j2++)
        acc[i2][j2] = MFMA16(af[i2], bfr[j2], acc[i2][j2]);
  }
  __syncthreads();
  {
    int gch = (tid & 31) ^ ((tid >> 5) & 7);
    const u16* gCl = ctxt + (size_t)bh*DHEAD*MFEAT + (size_t)(tid>>5)*MFEAT + gch*8;
    #pragma unroll
    for(int i=0;i<4;i++)
      GLOAD16(gCl + (size_t)i*16*MFEAT, &smA[i*4096 + w*512]);
  }
  #pragma unroll
  for(int i2=0;i2<2;i2++){
    #pragma unroll
    for(int r=0;r<4;r++){
      float v = fmaxf(fmaxf(acc[i2][0][r],acc[i2][1][r]), fmaxf(acc[i2][2][r],acc[i2][3][r]));
      v = fmaxf(v, __shfl_xor(v,1)); v = fmaxf(v, __shfl_xor(v,2));
      v = fmaxf(v, __shfl_xor(v,4)); v = fmaxf(v, __shfl_xor(v,8));
      if(li==0) wred[g][wq][i2*16 + hi*4 + r] = v;
    }
  }
  __builtin_amdgcn_sched_barrier(0);
  asm volatile("s_waitcnt lgkmcnt(0)");
  __builtin_amdgcn_s_barrier();
  __builtin_amdgcn_sched_barrier(0);
  #pragma unroll
  for(int i2=0;i2<2;i2++){
    #pragma unroll
    for(int r=0;r<4;r++){
      int rl = i2*16 + hi*4 + r;
      int row = g*32 + rl;
      float rm = fmaxf(fmaxf(wred[g][0][rl],wred[g][1][rl]),
                       fmaxf(wred[g][2][rl],wred[g][3][rl]));
      float dsum = 0.f;
      #pragma unroll
      for(int j2=0;j2<4;j2++){
        int col = wq*64 + j2*16 + li;
        float u = acc[i2][j2][r]*DNRM;
        u16 eb = f2bf(SMF*(__expf(u - dgs[row] - rm) + EPSF));
        smQ[row*264 + col] = eb;
        dsum += bf2f(eb)*ksl[col];
      }
      dsum += __shfl_xor(dsum,1); dsum += __shfl_xor(dsum,2);
      dsum += __shfl_xor(dsum,4); dsum += __shfl_xor(dsum,8);
      if(li==0) wden[g][wq][rl] = dsum;
    }
  }
  __builtin_amdgcn_sched_barrier(0);
  asm volatile("s_waitcnt vmcnt(0) lgkmcnt(0)");
  __builtin_amdgcn_s_barrier();
  __builtin_amdgcn_sched_barrier(0);
  if(tid < 64){
    int gg = tid >> 5, rr = tid & 31;
    denl[tid] = wden[gg][0][rr]+wden[gg][1][rr]+wden[gg][2][rr]+wden[gg][3][rr];
  }
  int d4 = w >> 1, g2 = w & 1;
  f32x4 acc2[2] = {};
  #pragma unroll
  for(int s=0;s<8;s++){
    int kc = s*4 + hi;
    int bc = d4*16 + li;
    bf16x8 bf = *(const bf16x8*)&smA[bc*256 + ((kc ^ (bc&7))<<3)];
    #pragma unroll
    for(int t=0;t<2;t++){
      int ar = g2*32 + t*16 + li;
      bf16x8 aa = *(const bf16x8*)&smQ[ar*264 + kc*8];
      acc2[t] = MFMA16(aa, bf, acc2[t]);
    }
  }
  __syncthreads();
  int nbase = r0 & (SEQ-1);
  #pragma unroll
  for(int t=0;t<2;t++){
    #pragma unroll
    for(int r=0;r<4;r++){
      int nl = g2*32 + t*16 + hi*4 + r;
      float di = 1.0f/denl[nl];
      o[((size_t)b*SEQ + nbase + nl)*DMODEL + h*DHEAD + d4*16 + li] = f2bf(acc2[t][r]*di);
    }
  }
}

// ---------------- ctx_t: m-tile 32, grid (8,BHN), 2 blocks/CU, depth-2 pipeline ----------------
__global__ __launch_bounds__(256)
void k_ctx(const u16* __restrict__ vt, const u16* __restrict__ kpt,
           u16* __restrict__ ctxt){
  __shared__ u16 As[2][64*64];
  __shared__ u16 Bs[2][32*64];
  int tid = threadIdx.x, w = tid >> 6, lane = tid & 63;
  int wr = w >> 1, wc = w & 1;
  int hi = lane >> 4, li = lane & 15;
  int bh = blockIdx.y, mb = blockIdx.x*32;
  int lr = lane >> 3;
  int lc = (lane & 7) ^ lr;
  const u16* gA = vt  + (size_t)bh*DHEAD*SEQ + (size_t)(w*8 + lr)*SEQ + lc*8;
  const u16* gB = kpt + ((size_t)bh*MFEAT + mb + w*8 + lr)*SEQ + lc*8;
  f32x4 acc[2][1] = {};
#define STAGE_CTX(b,k0) { \
    GLOAD16(gA + (k0),                  &As[b][(w*8)*64]);      \
    GLOAD16(gA + (size_t)32*SEQ + (k0), &As[b][(32+w*8)*64]);   \
    GLOAD16(gB + (k0),                  &Bs[b][(w*8)*64]); }
  int nk = SEQ/64;
  STAGE_CTX(0, 0)
  STAGE_CTX(1, 64)
  for(int t=0; t<nk; ++t){
    __builtin_amdgcn_sched_barrier(0);
    if(t+1 < nk){ asm volatile("s_waitcnt vmcnt(3)"); }
    else        { asm volatile("s_waitcnt vmcnt(0)"); }
    __builtin_amdgcn_s_barrier();
    __builtin_amdgcn_sched_barrier(0);
    const u16* pa = &As[t&1][0];
    const u16* pb = &Bs[t&1][0];
    #pragma unroll
    for(int ks=0;ks<2;ks++){
      bf16x8 af[2], bfr;
      int kc = ks*4 + hi;
      #pragma unroll
      for(int q=0;q<2;q++){
        int ar = wr*32 + q*16 + li;
        af[q] = *(const bf16x8*)&pa[ar*64 + ((kc ^ (ar&7))<<3)];
      }
      {
        int bc = wc*16 + li;
        bfr = *(const bf16x8*)&pb[bc*64 + ((kc ^ (bc&7))<<3)];
      }
      __builtin_amdgcn_s_setprio(1);
      #pragma unroll
      for(int i2=0;i2<2;i2++)
        acc[i2][0] = MFMA16(af[i2], bfr, acc[i2][0]);
      __builtin_amdgcn_s_setprio(0);
    }
    __builtin_amdgcn_sched_barrier(0);
    __builtin_amdgcn_s_barrier();
    __builtin_amdgcn_sched_barrier(0);
    if(t+2 < nk){ STAGE_CTX(t&1, (size_t)(t+2)*64) }
  }
#undef STAGE_CTX
  #pragma unroll
  for(int i2=0;i2<2;i2++){
    int m = mb + wc*16 + li;
    #pragma unroll
    for(int r=0;r<4;r++){
      int dh = wr*32 + i2*16 + hi*4 + r;
      ctxt[((size_t)bh*DHEAD + dh)*MFEAT + m] = f2bf(acc[i2][0][r]);
    }
  }
}

extern "C" void kernel_launch(void* const* d_in, const int* in_sizes, int n_in,
                              void* d_out, int out_size, void* d_ws, size_t ws_size,
                              hipStream_t stream){
  (void)in_sizes; (void)n_in; (void)out_size; (void)ws_size;
  const float* x    = (const float*)d_in[0];
  const float* proj = (const float*)d_in[1];
  const float* ln1g = (const float*)d_in[2];
  const float* ln1b = (const float*)d_in[3];
  const float* wq   = (const float*)d_in[4];
  const float* wk   = (const float*)d_in[5];
  const float* wv   = (const float*)d_in[6];
  const float* wo   = (const float*)d_in[7];
  const float* bo   = (const float*)d_in[8];
  const float* ln2g = (const float*)d_in[9];
  const float* ln2b = (const float*)d_in[10];
  const float* w1   = (const float*)d_in[11];
  const float* b1   = (const float*)d_in[12];
  const float* w2   = (const float*)d_in[13];
  const float* b2   = (const float*)d_in[14];
  float* xo = (float*)d_out;

  // workspace ~110 MB
  char* ws = (char*)d_ws;
  u16* bufH  = (u16*)ws;  ws += (size_t)TOK*DMODEL*2;
  u16* bufA  = (u16*)ws;  ws += (size_t)TOK*DMODEL*2;
  u16* featb = (u16*)ws;  ws += (size_t)BHN*SEQ*MFEAT*2;
  u16* ctxt  = (u16*)ws;  ws += (size_t)BHN*DHEAD*MFEAT*2;
  u16* wT    = (u16*)ws;  ws += (size_t)3*1048576*2;
  u16* pjb   = (u16*)ws;  ws += (size_t)LNUM*MFEAT*DHEAD*2;
  float* ksum= (float*)ws; ws += (size_t)BHN*MFEAT*4;
  float* kmax= (float*)ws; ws += 256;

  u16* wqT = wT;
  u16* wkT = wT +  262144;
  u16* wvT = wT +  524288;
  u16* woT = wT +  786432;
  u16* w1T = wT + 1048576;
  u16* w2T = wT + 2097152;

  k_addpe<<<(TOK*DMODEL)/256, 256, 0, stream>>>(x, xo);
  k_pcvt<<<(LNUM*MFEAT*DHEAD)/256, 256, 0, stream>>>(proj, pjb);

  for(int l=0; l<LNUM; l++){
    const u16* pj_l = pjb + (size_t)l*MFEAT*DHEAD;
    k_wcvt_all<<<769, 256, 0, stream>>>(wq + (size_t)l*262144, wk + (size_t)l*262144,
                                        wv + (size_t)l*262144, wo + (size_t)l*262144,
                                        w1 + (size_t)l*1048576, w2 + (size_t)l*1048576,
                                        wqT, wkT, wvT, woT, w1T, w2T, kmax);
    k_ln<<<TOK, 256, 0, stream>>>(xo, ln1g + l*DMODEL, ln1b + l*DMODEL, bufH);
    // K path: k -> u_t(f16)+kmax -> kp_t(bf16)+ksum (in place)
    k_mm8<1><<<dim3(4,64), 512, 0, stream>>>(bufH, wkT, nullptr, bufA, DMODEL, DMODEL);
    k_ku<<<(BHN*SEQ)/128, 256, 0, stream>>>(bufA, pj_l, featb, kmax);
    k_kexp<<<(BHN*MFEAT)/8, 256, 0, stream>>>(featb, kmax, ksum);
    // V path: v_t -> ctx_t
    k_mm8<4><<<dim3(4,64), 512, 0, stream>>>(bufH, wvT, nullptr, bufA, DMODEL, DMODEL);
    k_ctx<<<dim3(8,BHN), 256, 0, stream>>>(bufA, featb, ctxt);
    // Q path fused: q -> qp (LDS) -> o  -> wo-GEMM (residual add)
    k_mm8<1><<<dim3(4,64), 512, 0, stream>>>(bufH, wqT, nullptr, bufA, DMODEL, DMODEL);
    k_feato<<<(BHN*SEQ)/64, 512, 0, stream>>>(bufA, pj_l, ctxt, ksum, bufH);
    k_mm8<2><<<dim3(4,64), 512, 0, stream>>>(bufH, woT, bo + l*DMODEL, xo, DMODEL, DMODEL);
    // FFN: w1/w2 on the 128-tile k_mm (4 blocks/CU TLP wins at these grids)
    k_ln<<<TOK, 256, 0, stream>>>(xo, ln2g + l*DMODEL, ln2b + l*DMODEL, bufA);
    k_mm<3><<<dim3(16,128), 256, 0, stream>>>(bufA, w1T, b1 + l*DFF, featb, DFF, DMODEL);
    k_mm<2><<<dim3(4,128), 256, 0, stream>>>(featb, w2T, b2 + l*DMODEL, xo, DMODEL, DFF);
  }
}

// Round 18
// 2037.732 us; speedup vs baseline: 1.0800x; 1.0800x over previous
//
#include <hip/hip_runtime.h>
#include <math.h>

#define LNUM 6
#define HNUM 8
#define DMODEL 512
#define DHEAD 64
#define MFEAT 256
#define BATCH 8
#define SEQ 2048
#define TOK (BATCH*SEQ)
#define BHN (BATCH*HNUM)
#define DFF 2048
#define EPSF 1e-4f
#define LN_EPS 1e-5f
#define DNRM 0.35355339059327373f
#define SMF 0.0625f

typedef unsigned short u16;
typedef __attribute__((ext_vector_type(8))) short bf16x8;
typedef __attribute__((ext_vector_type(4))) float f32x4;
#define MFMA16(a,b,c) __builtin_amdgcn_mfma_f32_16x16x32_bf16(a,b,c,0,0,0)

// async global->LDS, 16B per lane; LDS dest = wave-uniform base + lane*16
#define GLOAD16(g,l) __builtin_amdgcn_global_load_lds( \
    (const __attribute__((address_space(1))) void*)(g), \
    (__attribute__((address_space(3))) void*)(l), 16, 0, 0)

__device__ __forceinline__ u16 f2bf(float f){
  unsigned int u = __float_as_uint(f);
  u = (u + 0x7fffu + ((u >> 16) & 1u)) >> 16;
  return (u16)u;
}
__device__ __forceinline__ float bf2f(u16 s){
  return __uint_as_float(((unsigned int)s) << 16);
}
__device__ __forceinline__ void atomicMaxF(float* addr, float val){
  if(val >= 0.f) atomicMax((int*)addr, __float_as_int(val));
  else           atomicMin((unsigned int*)addr, __float_as_uint(val));
}
// gelu tanh-approx: z * sigmoid(2*(c1 z + c2 z^3))
__device__ __forceinline__ float fast_gelu(float z){
  float g2 = z*(1.5957691216f + 0.07135481628f*z*z);
  return z / (1.0f + __expf(-g2));
}

// ---------------- x = x + sinusoidal PE ----------------
__global__ void k_addpe(const float* __restrict__ x, float* __restrict__ xo){
  int idx = blockIdx.x*256 + threadIdx.x;
  int d = idx & (DMODEL-1);
  int n = (idx >> 9) & (SEQ-1);
  int j = d >> 1;
  float freq = expf((float)(2*j) * (-9.210340371976184f / (float)DMODEL));
  float ang = (float)n * freq;
  float pe = (d & 1) ? cosf(ang) : sinf(ang);
  xo[idx] = x[idx] + pe;
}

// ---------------- LayerNorm (512) -> bf16 ----------------
__global__ void k_ln(const float* __restrict__ x, const float* __restrict__ g,
                     const float* __restrict__ bv, u16* __restrict__ out){
  __shared__ float sred[8];
  int t = blockIdx.x, tid = threadIdx.x;
  const float2 v = ((const float2*)(x + (size_t)t*DMODEL))[tid];
  float s = v.x + v.y;
  #pragma unroll
  for(int o=32;o;o>>=1) s += __shfl_down(s,o);
  if((tid&63)==0) sred[tid>>6] = s;
  __syncthreads();
  if(tid==0) sred[4] = (sred[0]+sred[1]+sred[2]+sred[3]) * (1.0f/DMODEL);
  __syncthreads();
  float mu = sred[4];
  float dx = v.x - mu, dy = v.y - mu;
  float s2 = dx*dx + dy*dy;
  #pragma unroll
  for(int o=32;o;o>>=1) s2 += __shfl_down(s2,o);
  if((tid&63)==0) sred[tid>>6] = s2;
  __syncthreads();
  if(tid==0) sred[5] = rsqrtf((sred[0]+sred[1]+sred[2]+sred[3])*(1.0f/DMODEL) + LN_EPS);
  __syncthreads();
  float rs = sred[5];
  const float2 gg = ((const float2*)g)[tid];
  const float2 bb = ((const float2*)bv)[tid];
  ushort2 o2; o2.x = f2bf(dx*rs*gg.x + bb.x); o2.y = f2bf(dy*rs*gg.y + bb.y);
  ((ushort2*)(out + (size_t)t*DMODEL))[tid] = o2;
}

__global__ void k_pcvt(const float* __restrict__ p, u16* __restrict__ pb){
  int i = blockIdx.x*256 + threadIdx.x;
  pb[i] = f2bf(p[i]);
}

// ---------------- all weight transposes + ksum/kmax init in ONE dispatch ----------------
__global__ void k_wcvt_all(const float* __restrict__ wq, const float* __restrict__ wk,
                           const float* __restrict__ wv, const float* __restrict__ wo,
                           const float* __restrict__ w1, const float* __restrict__ w2,
                           u16* __restrict__ wqT, u16* __restrict__ wkT,
                           u16* __restrict__ wvT, u16* __restrict__ woT,
                           u16* __restrict__ w1T, u16* __restrict__ w2T,
                           float* __restrict__ ksum, float* __restrict__ kmax){
  int bid = blockIdx.x;
  if(bid >= 768){
    int i = (bid-768)*256 + threadIdx.x;
    ksum[i] = 0.f;
    if(i < BHN) kmax[i] = -INFINITY;
    return;
  }
  const float* src; u16* dst; int K, N, bx, by;
  if(bid < 256){
    int which = bid >> 6, sub = bid & 63;
    src = which==0 ? wq : which==1 ? wk : which==2 ? wv : wo;
    dst = which==0 ? wqT : which==1 ? wkT : which==2 ? wvT : woT;
    K = 512; N = 512; bx = sub & 7; by = sub >> 3;
  } else if(bid < 512){
    int sub = bid - 256; src = w1; dst = w1T; K = 512; N = 2048; bx = sub & 31; by = sub >> 5;
  } else {
    int sub = bid - 512; src = w2; dst = w2T; K = 2048; N = 512; bx = sub & 7; by = sub >> 3;
  }
  __shared__ float sm[64][65];
  int kt = by*64, nt = bx*64;
  int t = threadIdx.x, c = t & 63, r4 = t >> 6;
  #pragma unroll
  for(int i=0;i<16;i++){
    int kl = i*4 + r4;
    sm[kl][c] = src[(size_t)(kt+kl)*N + nt + c];
  }
  __syncthreads();
  #pragma unroll
  for(int i=0;i<16;i++){
    int nl = i*4 + r4;
    dst[(size_t)(nt+nl)*K + kt + c] = f2bf(sm[c][nl]);
  }
}

// ---------------- MFMA GEMM, 128x128, BK=32, depth-2, counted vmcnt, 128-reg cap ----------------
template<int EPI>
__global__ __launch_bounds__(256,4)
void k_mm(const u16* __restrict__ A, const u16* __restrict__ Bt,
          const float* __restrict__ bias, void* __restrict__ Cv,
          int Nc, int K){
  __shared__ u16 As[2][128*32];
  __shared__ u16 Bs[2][128*32];
  int tid = threadIdx.x;
  int w = tid >> 6, lane = tid & 63;
  int wr = w >> 1, wc = w & 1;
  int hi = lane >> 4, li = lane & 15;
  int row0 = blockIdx.y*128, col0 = blockIdx.x*128;
  int lr = lane >> 2;
  int cs = (lane & 3) ^ ((lane >> 3) & 3);
  const u16* gA = A  + (size_t)(row0 + w*16 + lr)*K + cs*8;
  const u16* gB = Bt + (size_t)(col0 + w*16 + lr)*K + cs*8;
  int rb = li*32 + ((hi ^ ((li>>1)&3))<<3);
  f32x4 acc[4][4] = {};

#define STAGE_MM(b,k0) { \
    GLOAD16(gA + (k0),                &As[b][(w*16)*32]);      \
    GLOAD16(gA + (size_t)64*K + (k0), &As[b][(64+w*16)*32]);   \
    GLOAD16(gB + (k0),                &Bs[b][(w*16)*32]);      \
    GLOAD16(gB + (size_t)64*K + (k0), &Bs[b][(64+w*16)*32]); }

  int nk = K >> 5;
  STAGE_MM(0, 0)
  STAGE_MM(1, 32)
  for(int t=0; t<nk; ++t){
    __builtin_amdgcn_sched_barrier(0);
    if(t+1 < nk){ asm volatile("s_waitcnt vmcnt(4)"); }
    else        { asm volatile("s_waitcnt vmcnt(0)"); }
    __builtin_amdgcn_s_barrier();
    __builtin_amdgcn_sched_barrier(0);
    const u16* pa = &As[t&1][0];
    const u16* pb = &Bs[t&1][0];
    bf16x8 bfr[4];
    #pragma unroll
    for(int q=0;q<4;q++) bfr[q] = *(const bf16x8*)&pb[rb + wc*2048 + q*512];
    __builtin_amdgcn_s_setprio(1);
    #pragma unroll
    for(int i2=0;i2<4;i2++){
      bf16x8 a = *(const bf16x8*)&pa[rb + wr*2048 + i2*512];
      #pragma unroll
      for(int j2=0;j2<4;j2++)
        acc[i2][j2] = MFMA16(a, bfr[j2], acc[i2][j2]);
    }
    __builtin_amdgcn_s_setprio(0);
    __builtin_amdgcn_sched_barrier(0);
    __builtin_amdgcn_s_barrier();
    __builtin_amdgcn_sched_barrier(0);
    if(t+2 < nk){ STAGE_MM(t&1, (size_t)(t+2)*32) }
  }
#undef STAGE_MM

  #pragma unroll
  for(int i2=0;i2<4;i2++){
    #pragma unroll
    for(int j2=0;j2<4;j2++){
      int col = col0 + wc*64 + j2*16 + li;
      float bcol = (EPI==2 || EPI==3) ? bias[col] : 0.f;
      if constexpr (EPI==4){
        int nb = row0 + wr*64 + i2*16 + hi*4;
        int b = nb >> 11, n = nb & (SEQ-1);
        int h = col >> 6, dh = col & 63;
        ushort4 pk;
        pk.x = f2bf(acc[i2][j2][0]); pk.y = f2bf(acc[i2][j2][1]);
        pk.z = f2bf(acc[i2][j2][2]); pk.w = f2bf(acc[i2][j2][3]);
        *(ushort4*)((u16*)Cv + (((size_t)(b*HNUM+h)*DHEAD + dh)*SEQ + n)) = pk;
      } else {
        #pragma unroll
        for(int r=0;r<4;r++){
          int row = row0 + wr*64 + i2*16 + hi*4 + r;
          float v = acc[i2][j2][r];
          if constexpr (EPI==1){
            int b = row >> 11, n = row & (SEQ-1);
            int h = col >> 6, dh = col & 63;
            ((u16*)Cv)[((size_t)(b*HNUM+h)*SEQ + n)*DHEAD + dh] = f2bf(v);
          } else if constexpr (EPI==2){
            ((float*)Cv)[(size_t)row*Nc + col] += v + bcol;
          } else {
            ((u16*)Cv)[(size_t)row*Nc + col] = f2bf(fast_gelu(v + bcol));
          }
        }
      }
    }
  }
}

// ---------------- MFMA GEMM, 256x128 tile, BK=64, 3-buffer phase-split ----------------
template<int EPI>
__global__ __launch_bounds__(512)
void k_mm8(const u16* __restrict__ A, const u16* __restrict__ Bt,
           const float* __restrict__ bias, void* __restrict__ Cv,
           int Nc, int K){
  __shared__ u16 Ab[3][256*64];
  __shared__ u16 Bb[3][128*64];
  int tid = threadIdx.x;
  int w = tid >> 6, lane = tid & 63;
  int wr = w >> 1, wc = w & 1;
  int hi = lane >> 4, li = lane & 15;
  int row0 = blockIdx.y*256, col0 = blockIdx.x*128;
  int lr = lane >> 3;
  int lc = (lane & 7) ^ lr;
  const u16* gA = A  + (size_t)(row0 + w*8 + lr)*K + lc*8;
  const u16* gB = Bt + (size_t)(col0 + w*8 + lr)*K + lc*8;
  f32x4 acc[4][4] = {};

#define STG8(buf,k0) { \
    GLOAD16(gA + (k0),                  &Ab[buf][w*512]);          \
    GLOAD16(gA + (size_t)64*K  + (k0),  &Ab[buf][4096  + w*512]);  \
    GLOAD16(gA + (size_t)128*K + (k0),  &Ab[buf][8192  + w*512]);  \
    GLOAD16(gA + (size_t)192*K + (k0),  &Ab[buf][12288 + w*512]);  \
    GLOAD16(gB + (k0),                  &Bb[buf][w*512]);          \
    GLOAD16(gB + (size_t)64*K  + (k0),  &Bb[buf][4096  + w*512]); }

  int nk = K >> 6;
  STG8(0, 0)
  STG8(1, 64)
  for(int t=0; t<nk; ++t){
    int buf = t % 3;
    int nbuf = (t+2) % 3;
    size_t nk0 = (size_t)(t+2)*64;
    __builtin_amdgcn_sched_barrier(0);
    if(t+1 < nk){ asm volatile("s_waitcnt vmcnt(6)"); }
    else        { asm volatile("s_waitcnt vmcnt(0)"); }
    __builtin_amdgcn_s_barrier();
    __builtin_amdgcn_sched_barrier(0);
    const u16* pa = &Ab[buf][0];
    const u16* pb = &Bb[buf][0];
    bf16x8 bfr[2][4], af[2][2];
    #pragma unroll
    for(int kk=0;kk<2;kk++){
      int kc = kk*4 + hi;
      #pragma unroll
      for(int j=0;j<4;j++){
        int bc = wc*64 + j*16 + li;
        bfr[kk][j] = *(const bf16x8*)&pb[bc*64 + ((kc ^ (bc&7))<<3)];
      }
      #pragma unroll
      for(int q=0;q<2;q++){
        int ar = wr*64 + q*16 + li;
        af[kk][q] = *(const bf16x8*)&pa[ar*64 + ((kc ^ (ar&7))<<3)];
      }
    }
    if(t+2 < nk){
      GLOAD16(gA + nk0,                  &Ab[nbuf][w*512]);
      GLOAD16(gA + (size_t)64*K  + nk0,  &Ab[nbuf][4096  + w*512]);
      GLOAD16(gA + (size_t)128*K + nk0,  &Ab[nbuf][8192  + w*512]);
    }
    __builtin_amdgcn_s_setprio(1);
    #pragma unroll
    for(int kk=0;kk<2;kk++)
      #pragma unroll
      for(int q=0;q<2;q++)
        #pragma unroll
        for(int j=0;j<4;j++)
          acc[q][j] = MFMA16(af[kk][q], bfr[kk][j], acc[q][j]);
    __builtin_amdgcn_s_setprio(0);
    __builtin_amdgcn_s_barrier();
    bf16x8 af2[2][2];
    #pragma unroll
    for(int kk=0;kk<2;kk++){
      int kc = kk*4 + hi;
      #pragma unroll
      for(int q=0;q<2;q++){
        int ar = wr*64 + (q+2)*16 + li;
        af2[kk][q] = *(const bf16x8*)&pa[ar*64 + ((kc ^ (ar&7))<<3)];
      }
    }
    if(t+2 < nk){
      GLOAD16(gA + (size_t)192*K + nk0,  &Ab[nbuf][12288 + w*512]);
      GLOAD16(gB + nk0,                  &Bb[nbuf][w*512]);
      GLOAD16(gB + (size_t)64*K  + nk0,  &Bb[nbuf][4096  + w*512]);
    }
    __builtin_amdgcn_s_setprio(1);
    #pragma unroll
    for(int kk=0;kk<2;kk++)
      #pragma unroll
      for(int q=0;q<2;q++)
        #pragma unroll
        for(int j=0;j<4;j++)
          acc[q+2][j] = MFMA16(af2[kk][q], bfr[kk][j], acc[q+2][j]);
    __builtin_amdgcn_s_setprio(0);
    __builtin_amdgcn_s_barrier();
  }
#undef STG8

  #pragma unroll
  for(int i2=0;i2<4;i2++){
    #pragma unroll
    for(int j2=0;j2<4;j2++){
      int col = col0 + wc*64 + j2*16 + li;
      float bcol = (EPI==2 || EPI==3) ? bias[col] : 0.f;
      if constexpr (EPI==4){
        int nb = row0 + wr*64 + i2*16 + hi*4;
        int b = nb >> 11, n = nb & (SEQ-1);
        int h = col >> 6, dh = col & 63;
        ushort4 pk;
        pk.x = f2bf(acc[i2][j2][0]); pk.y = f2bf(acc[i2][j2][1]);
        pk.z = f2bf(acc[i2][j2][2]); pk.w = f2bf(acc[i2][j2][3]);
        *(ushort4*)((u16*)Cv + (((size_t)(b*HNUM+h)*DHEAD + dh)*SEQ + n)) = pk;
      } else {
        #pragma unroll
        for(int r=0;r<4;r++){
          int row = row0 + wr*64 + i2*16 + hi*4 + r;
          float v = acc[i2][j2][r];
          if constexpr (EPI==1){
            int b = row >> 11, n = row & (SEQ-1);
            int h = col >> 6, dh = col & 63;
            ((u16*)Cv)[((size_t)(b*HNUM+h)*SEQ + n)*DHEAD + dh] = f2bf(v);
          } else if constexpr (EPI==2){
            ((float*)Cv)[(size_t)row*Nc + col] += v + bcol;
          } else {
            ((u16*)Cv)[(size_t)row*Nc + col] = f2bf(fast_gelu(v + bcol));
          }
        }
      }
    }
  }
}

// ---------------- K max pass: 128 rows/block, streaming acc ----------------
__global__ __launch_bounds__(256)
void k_kmax(const u16* __restrict__ xg, const u16* __restrict__ pjb,
            float* __restrict__ kmax){
  __shared__ u16 pj[256*64];
  __shared__ u16 xs[128*64];
  __shared__ float wred[4];
  int tid = threadIdx.x, w = tid >> 6, lane = tid & 63;
  int hi = lane >> 4, li = lane & 15;
  int r0 = blockIdx.x * 128;
  int bh = r0 >> 11;
  #pragma unroll
  for(int i=0;i<8;i++){
    int idx = i*256 + tid;
    int m = idx >> 3, c = idx & 7;
    bf16x8 v = *(const bf16x8*)(pjb + m*64 + c*8);
    *(bf16x8*)&pj[m*64 + ((c ^ (m&7))<<3)] = v;
  }
  #pragma unroll
  for(int i=0;i<4;i++){
    int idx = i*256 + tid;
    int m = idx >> 3, c = idx & 7;
    bf16x8 v = *(const bf16x8*)(xg + (size_t)(r0+m)*64 + c*8);
    *(bf16x8*)&xs[m*64 + ((c ^ (m&7))<<3)] = v;
  }
  __syncthreads();
  bf16x8 bfr[2][4];
  #pragma unroll
  for(int ks=0;ks<2;ks++){
    int kc = ks*4 + hi;
    #pragma unroll
    for(int t=0;t<4;t++){
      int bc = w*64 + t*16 + li;
      bfr[ks][t] = *(const bf16x8*)&pj[bc*64 + ((kc ^ (bc&7))<<3)];
    }
  }
  float mx = -1e30f;
  #pragma unroll
  for(int i8=0;i8<8;i8++){
    f32x4 acc[4] = {};
    #pragma unroll
    for(int ks=0;ks<2;ks++){
      int kc = ks*4 + hi;
      int ar = i8*16 + li;
      bf16x8 af = *(const bf16x8*)&xs[ar*64 + ((kc ^ (ar&7))<<3)];
      #pragma unroll
      for(int j2=0;j2<4;j2++)
        acc[j2] = MFMA16(af, bfr[ks][j2], acc[j2]);
    }
    #pragma unroll
    for(int j2=0;j2<4;j2++)
      #pragma unroll
      for(int r=0;r<4;r++) mx = fmaxf(mx, acc[j2][r]);
  }
  #pragma unroll
  for(int o=32;o;o>>=1) mx = fmaxf(mx, __shfl_xor(mx,o));
  if(lane==0) wred[w] = mx;
  __syncthreads();
  if(tid==0){
    float m2 = fmaxf(fmaxf(wred[0],wred[1]), fmaxf(wred[2],wred[3]));
    atomicMaxF(&kmax[bh], m2*DNRM);
  }
}

// ---------------- K feature pass: 128 rows/block, kp_t + ksum, register diag ----------------
__global__ __launch_bounds__(256)
void k_kfeat(const u16* __restrict__ xg, const u16* __restrict__ pjb,
             u16* __restrict__ outp, const float* __restrict__ kmax,
             float* __restrict__ ksum){
  __shared__ u16 pj[256*64];
  __shared__ u16 xs[128*64];
  __shared__ float dgs[128];
  int tid = threadIdx.x, w = tid >> 6, lane = tid & 63;
  int hi = lane >> 4, li = lane & 15;
  int r0 = blockIdx.x * 128;
  int bh = r0 >> 11;
  int nbase = r0 & (SEQ-1);
  #pragma unroll
  for(int i=0;i<8;i++){
    int idx = i*256 + tid;
    int m = idx >> 3, c = idx & 7;
    bf16x8 v = *(const bf16x8*)(pjb + m*64 + c*8);
    *(bf16x8*)&pj[m*64 + ((c ^ (m&7))<<3)] = v;
  }
  #pragma unroll
  for(int i=0;i<4;i++){
    int idx = i*256 + tid;
    int m = idx >> 3, c = idx & 7;
    bf16x8 v = *(const bf16x8*)(xg + (size_t)(r0+m)*64 + c*8);
    *(bf16x8*)&xs[m*64 + ((c ^ (m&7))<<3)] = v;
    float s = 0.f;
    #pragma unroll
    for(int j=0;j<8;j++){ float t = bf2f((u16)v[j]); s += t*t; }
    s += __shfl_xor(s,1); s += __shfl_xor(s,2); s += __shfl_xor(s,4);
    if((tid&7)==0) dgs[m] = 0.5f*DNRM*DNRM*s;
  }
  __syncthreads();
  bf16x8 bfr[2][4];
  #pragma unroll
  for(int ks=0;ks<2;ks++){
    int kc = ks*4 + hi;
    #pragma unroll
    for(int t=0;t<4;t++){
      int bc = w*64 + t*16 + li;
      bfr[ks][t] = *(const bf16x8*)&pj[bc*64 + ((kc ^ (bc&7))<<3)];
    }
  }
  float km = kmax[bh];
  float csum[4] = {0.f,0.f,0.f,0.f};
  #pragma unroll
  for(int i8=0;i8<8;i8++){
    f32x4 acc[4] = {};
    #pragma unroll
    for(int ks=0;ks<2;ks++){
      int kc = ks*4 + hi;
      int ar = i8*16 + li;
      bf16x8 af = *(const bf16x8*)&xs[ar*64 + ((kc ^ (ar&7))<<3)];
      #pragma unroll
      for(int j2=0;j2<4;j2++)
        acc[j2] = MFMA16(af, bfr[ks][j2], acc[j2]);
    }
    #pragma unroll
    for(int j2=0;j2<4;j2++){
      int col = w*64 + j2*16 + li;
      ushort4 pk;
      float cpart = 0.f;
      #pragma unroll
      for(int r=0;r<4;r++){
        int rl = i8*16 + hi*4 + r;
        float u = acc[j2][r]*DNRM;
        u16 eb = f2bf(SMF*(__expf(u - dgs[rl] - km) + EPSF));
        ((u16*)&pk)[r] = eb;
        cpart += bf2f(eb);
      }
      *(ushort4*)(outp + ((size_t)(bh*MFEAT + col)*SEQ + nbase + i8*16 + hi*4)) = pk;
      csum[j2] += cpart;
    }
  }
  #pragma unroll
  for(int j2=0;j2<4;j2++){
    float v = csum[j2];
    v += __shfl_xor(v,16); v += __shfl_xor(v,32);
    if(hi==0) atomicAdd(&ksum[bh*MFEAT + w*64 + j2*16 + li], v);
  }
}

// ---------------- fused Q-feature + PV, 512 threads / 64 rows per block ----------------
__global__ __launch_bounds__(512)
void k_feato(const u16* __restrict__ xg, const u16* __restrict__ pjb,
             const u16* __restrict__ ctxt, const float* __restrict__ ksum,
             u16* __restrict__ o){
  __shared__ u16 smA[16384];
  __shared__ u16 smX[4096];
  __shared__ u16 smQ[64*264];
  __shared__ float dgs[64];
  __shared__ float wred[2][4][32];
  __shared__ float wden[2][4][32];
  __shared__ float ksl[256];
  __shared__ float denl[64];
  int tid = threadIdx.x, w = tid >> 6, lane = tid & 63;
  int hi = lane >> 4, li = lane & 15;
  int g = w >> 2, wq = w & 3;
  int r0 = blockIdx.x * 64;
  int bh = r0 >> 11;
  int b = bh >> 3, h = bh & 7;
  #pragma unroll
  for(int i=0;i<4;i++){
    int idx = i*512 + tid;
    int m = idx >> 3, c = idx & 7;
    bf16x8 v = *(const bf16x8*)(pjb + m*64 + c*8);
    *(bf16x8*)&smA[m*64 + ((c ^ (m&7))<<3)] = v;
  }
  {
    int m = tid >> 3, c = tid & 7;
    bf16x8 v = *(const bf16x8*)(xg + (size_t)(r0+m)*64 + c*8);
    *(bf16x8*)&smX[m*64 + ((c ^ (m&7))<<3)] = v;
    float s = 0.f;
    #pragma unroll
    for(int j=0;j<8;j++){ float t = bf2f((u16)v[j]); s += t*t; }
    s += __shfl_xor(s,1); s += __shfl_xor(s,2); s += __shfl_xor(s,4);
    if((tid&7)==0) dgs[m] = 0.5f*DNRM*DNRM*s;
  }
  if(tid < 256) ksl[tid] = ksum[bh*MFEAT + tid];
  __syncthreads();
  f32x4 acc[2][4] = {};
  #pragma unroll
  for(int ks=0;ks<2;ks++){
    bf16x8 af[2], bfr[4];
    int kc = ks*4 + hi;
    #pragma unroll
    for(int t=0;t<2;t++){
      int ar = g*32 + t*16 + li;
      af[t] = *(const bf16x8*)&smX[ar*64 + ((kc ^ (ar&7))<<3)];
    }
    #pragma unroll
    for(int t=0;t<4;t++){
      int bc = wq*64 + t*16 + li;
      bfr[t] = *(const bf16x8*)&smA[bc*64 + ((kc ^ (bc&7))<<3)];
    }
    #pragma unroll
    for(int i2=0;i2<2;i2++)
      #pragma unroll
      for(int j2=0;j2<4;j2++)
        acc[i2][j2] = MFMA16(af[i2], bfr[j2], acc[i2][j2]);
  }
  __syncthreads();
  {
    int gch = (tid & 31) ^ ((tid >> 5) & 7);
    const u16* gCl = ctxt + (size_t)bh*DHEAD*MFEAT + (size_t)(tid>>5)*MFEAT + gch*8;
    #pragma unroll
    for(int i=0;i<4;i++)
      GLOAD16(gCl + (size_t)i*16*MFEAT, &smA[i*4096 + w*512]);
  }
  #pragma unroll
  for(int i2=0;i2<2;i2++){
    #pragma unroll
    for(int r=0;r<4;r++){
      float v = fmaxf(fmaxf(acc[i2][0][r],acc[i2][1][r]), fmaxf(acc[i2][2][r],acc[i2][3][r]));
      v = fmaxf(v, __shfl_xor(v,1)); v = fmaxf(v, __shfl_xor(v,2));
      v = fmaxf(v, __shfl_xor(v,4)); v = fmaxf(v, __shfl_xor(v,8));
      if(li==0) wred[g][wq][i2*16 + hi*4 + r] = v;
    }
  }
  __builtin_amdgcn_sched_barrier(0);
  asm volatile("s_waitcnt lgkmcnt(0)");
  __builtin_amdgcn_s_barrier();
  __builtin_amdgcn_sched_barrier(0);
  #pragma unroll
  for(int i2=0;i2<2;i2++){
    #pragma unroll
    for(int r=0;r<4;r++){
      int rl = i2*16 + hi*4 + r;
      int row = g*32 + rl;
      float rm = fmaxf(fmaxf(wred[g][0][rl],wred[g][1][rl]),
                       fmaxf(wred[g][2][rl],wred[g][3][rl]));
      float dsum = 0.f;
      #pragma unroll
      for(int j2=0;j2<4;j2++){
        int col = wq*64 + j2*16 + li;
        float u = acc[i2][j2][r]*DNRM;
        u16 eb = f2bf(SMF*(__expf(u - dgs[row] - rm) + EPSF));
        smQ[row*264 + col] = eb;
        dsum += bf2f(eb)*ksl[col];
      }
      dsum += __shfl_xor(dsum,1); dsum += __shfl_xor(dsum,2);
      dsum += __shfl_xor(dsum,4); dsum += __shfl_xor(dsum,8);
      if(li==0) wden[g][wq][rl] = dsum;
    }
  }
  __builtin_amdgcn_sched_barrier(0);
  asm volatile("s_waitcnt vmcnt(0) lgkmcnt(0)");
  __builtin_amdgcn_s_barrier();
  __builtin_amdgcn_sched_barrier(0);
  if(tid < 64){
    int gg = tid >> 5, rr = tid & 31;
    denl[tid] = wden[gg][0][rr]+wden[gg][1][rr]+wden[gg][2][rr]+wden[gg][3][rr];
  }
  int d4 = w >> 1, g2 = w & 1;
  f32x4 acc2[2] = {};
  #pragma unroll
  for(int s=0;s<8;s++){
    int kc = s*4 + hi;
    int bc = d4*16 + li;
    bf16x8 bf = *(const bf16x8*)&smA[bc*256 + ((kc ^ (bc&7))<<3)];
    #pragma unroll
    for(int t=0;t<2;t++){
      int ar = g2*32 + t*16 + li;
      bf16x8 aa = *(const bf16x8*)&smQ[ar*264 + kc*8];
      acc2[t] = MFMA16(aa, bf, acc2[t]);
    }
  }
  __syncthreads();
  int nbase = r0 & (SEQ-1);
  #pragma unroll
  for(int t=0;t<2;t++){
    #pragma unroll
    for(int r=0;r<4;r++){
      int nl = g2*32 + t*16 + hi*4 + r;
      float di = 1.0f/denl[nl];
      o[((size_t)b*SEQ + nbase + nl)*DMODEL + h*DHEAD + d4*16 + li] = f2bf(acc2[t][r]*di);
    }
  }
}

// ---------------- ctx_t: m-tile 32, grid (8,BHN), 2 blocks/CU, depth-2 pipeline ----------------
__global__ __launch_bounds__(256)
void k_ctx(const u16* __restrict__ vt, const u16* __restrict__ kpt,
           u16* __restrict__ ctxt){
  __shared__ u16 As[2][64*64];
  __shared__ u16 Bs[2][32*64];
  int tid = threadIdx.x, w = tid >> 6, lane = tid & 63;
  int wr = w >> 1, wc = w & 1;
  int hi = lane >> 4, li = lane & 15;
  int bh = blockIdx.y, mb = blockIdx.x*32;
  int lr = lane >> 3;
  int lc = (lane & 7) ^ lr;
  const u16* gA = vt  + (size_t)bh*DHEAD*SEQ + (size_t)(w*8 + lr)*SEQ + lc*8;
  const u16* gB = kpt + ((size_t)bh*MFEAT + mb + w*8 + lr)*SEQ + lc*8;
  f32x4 acc[2][1] = {};
#define STAGE_CTX(b,k0) { \
    GLOAD16(gA + (k0),                  &As[b][(w*8)*64]);      \
    GLOAD16(gA + (size_t)32*SEQ + (k0), &As[b][(32+w*8)*64]);   \
    GLOAD16(gB + (k0),                  &Bs[b][(w*8)*64]); }
  int nk = SEQ/64;
  STAGE_CTX(0, 0)
  STAGE_CTX(1, 64)
  for(int t=0; t<nk; ++t){
    __builtin_amdgcn_sched_barrier(0);
    if(t+1 < nk){ asm volatile("s_waitcnt vmcnt(3)"); }
    else        { asm volatile("s_waitcnt vmcnt(0)"); }
    __builtin_amdgcn_s_barrier();
    __builtin_amdgcn_sched_barrier(0);
    const u16* pa = &As[t&1][0];
    const u16* pb = &Bs[t&1][0];
    #pragma unroll
    for(int ks=0;ks<2;ks++){
      bf16x8 af[2], bfr;
      int kc = ks*4 + hi;
      #pragma unroll
      for(int q=0;q<2;q++){
        int ar = wr*32 + q*16 + li;
        af[q] = *(const bf16x8*)&pa[ar*64 + ((kc ^ (ar&7))<<3)];
      }
      {
        int bc = wc*16 + li;
        bfr = *(const bf16x8*)&pb[bc*64 + ((kc ^ (bc&7))<<3)];
      }
      __builtin_amdgcn_s_setprio(1);
      #pragma unroll
      for(int i2=0;i2<2;i2++)
        acc[i2][0] = MFMA16(af[i2], bfr, acc[i2][0]);
      __builtin_amdgcn_s_setprio(0);
    }
    __builtin_amdgcn_sched_barrier(0);
    __builtin_amdgcn_s_barrier();
    __builtin_amdgcn_sched_barrier(0);
    if(t+2 < nk){ STAGE_CTX(t&1, (size_t)(t+2)*64) }
  }
#undef STAGE_CTX
  #pragma unroll
  for(int i2=0;i2<2;i2++){
    int m = mb + wc*16 + li;
    #pragma unroll
    for(int r=0;r<4;r++){
      int dh = wr*32 + i2*16 + hi*4 + r;
      ctxt[((size_t)bh*DHEAD + dh)*MFEAT + m] = f2bf(acc[i2][0][r]);
    }
  }
}

extern "C" void kernel_launch(void* const* d_in, const int* in_sizes, int n_in,
                              void* d_out, int out_size, void* d_ws, size_t ws_size,
                              hipStream_t stream){
  (void)in_sizes; (void)n_in; (void)out_size; (void)ws_size;
  const float* x    = (const float*)d_in[0];
  const float* proj = (const float*)d_in[1];
  const float* ln1g = (const float*)d_in[2];
  const float* ln1b = (const float*)d_in[3];
  const float* wq   = (const float*)d_in[4];
  const float* wk   = (const float*)d_in[5];
  const float* wv   = (const float*)d_in[6];
  const float* wo   = (const float*)d_in[7];
  const float* bo   = (const float*)d_in[8];
  const float* ln2g = (const float*)d_in[9];
  const float* ln2b = (const float*)d_in[10];
  const float* w1   = (const float*)d_in[11];
  const float* b1   = (const float*)d_in[12];
  const float* w2   = (const float*)d_in[13];
  const float* b2   = (const float*)d_in[14];
  float* xo = (float*)d_out;

  // workspace ~110 MB
  char* ws = (char*)d_ws;
  u16* bufH  = (u16*)ws;  ws += (size_t)TOK*DMODEL*2;
  u16* bufA  = (u16*)ws;  ws += (size_t)TOK*DMODEL*2;
  u16* featb = (u16*)ws;  ws += (size_t)BHN*SEQ*MFEAT*2;
  u16* ctxt  = (u16*)ws;  ws += (size_t)BHN*DHEAD*MFEAT*2;
  u16* wT    = (u16*)ws;  ws += (size_t)3*1048576*2;
  u16* pjb   = (u16*)ws;  ws += (size_t)LNUM*MFEAT*DHEAD*2;
  float* ksum= (float*)ws; ws += (size_t)BHN*MFEAT*4;
  float* kmax= (float*)ws; ws += 256;

  u16* wqT = wT;
  u16* wkT = wT +  262144;
  u16* wvT = wT +  524288;
  u16* woT = wT +  786432;
  u16* w1T = wT + 1048576;
  u16* w2T = wT + 2097152;

  k_addpe<<<(TOK*DMODEL)/256, 256, 0, stream>>>(x, xo);
  k_pcvt<<<(LNUM*MFEAT*DHEAD)/256, 256, 0, stream>>>(proj, pjb);

  for(int l=0; l<LNUM; l++){
    const u16* pj_l = pjb + (size_t)l*MFEAT*DHEAD;
    k_wcvt_all<<<832, 256, 0, stream>>>(wq + (size_t)l*262144, wk + (size_t)l*262144,
                                        wv + (size_t)l*262144, wo + (size_t)l*262144,
                                        w1 + (size_t)l*1048576, w2 + (size_t)l*1048576,
                                        wqT, wkT, wvT, woT, w1T, w2T, ksum, kmax);
    k_ln<<<TOK, 256, 0, stream>>>(xo, ln1g + l*DMODEL, ln1b + l*DMODEL, bufH);
    // K path: k -> kmax -> kp_t (+ksum atomics)
    k_mm8<1><<<dim3(4,64), 512, 0, stream>>>(bufH, wkT, nullptr, bufA, DMODEL, DMODEL);
    k_kmax<<<(BHN*SEQ)/128, 256, 0, stream>>>(bufA, pj_l, kmax);
    k_kfeat<<<(BHN*SEQ)/128, 256, 0, stream>>>(bufA, pj_l, featb, kmax, ksum);
    // V path: v_t -> ctx_t
    k_mm8<4><<<dim3(4,64), 512, 0, stream>>>(bufH, wvT, nullptr, bufA, DMODEL, DMODEL);
    k_ctx<<<dim3(8,BHN), 256, 0, stream>>>(bufA, featb, ctxt);
    // Q path fused: q -> qp (LDS) -> o  -> wo-GEMM (residual add)
    k_mm8<1><<<dim3(4,64), 512, 0, stream>>>(bufH, wqT, nullptr, bufA, DMODEL, DMODEL);
    k_feato<<<(BHN*SEQ)/64, 512, 0, stream>>>(bufA, pj_l, ctxt, ksum, bufH);
    k_mm8<2><<<dim3(4,64), 512, 0, stream>>>(bufH, woT, bo + l*DMODEL, xo, DMODEL, DMODEL);
    // FFN: w1/w2 on the 128-tile k_mm (4 blocks/CU TLP wins at these grids)
    k_ln<<<TOK, 256, 0, stream>>>(xo, ln2g + l*DMODEL, ln2b + l*DMODEL, bufA);
    k_mm<3><<<dim3(16,128), 256, 0, stream>>>(bufA, w1T, b1 + l*DFF, featb, DFF, DMODEL);
    k_mm<2><<<dim3(4,128), 256, 0, stream>>>(featb, w2T, b2 + l*DMODEL, xo, DMODEL, DFF);
  }
}

// Round 19
// 1983.646 us; speedup vs baseline: 1.1094x; 1.0273x over previous
//
#include <hip/hip_runtime.h>
#include <math.h>

#define LNUM 6
#define HNUM 8
#define DMODEL 512
#define DHEAD 64
#define MFEAT 256
#define BATCH 8
#define SEQ 2048
#define TOK (BATCH*SEQ)
#define BHN (BATCH*HNUM)
#define DFF 2048
#define EPSF 1e-4f
#define LN_EPS 1e-5f
#define DNRM 0.35355339059327373f
#define SMF 0.0625f

typedef unsigned short u16;
typedef __attribute__((ext_vector_type(8))) short bf16x8;
typedef __attribute__((ext_vector_type(4))) float f32x4;
#define MFMA16(a,b,c) __builtin_amdgcn_mfma_f32_16x16x32_bf16(a,b,c,0,0,0)

// async global->LDS, 16B per lane; LDS dest = wave-uniform base + lane*16
#define GLOAD16(g,l) __builtin_amdgcn_global_load_lds( \
    (const __attribute__((address_space(1))) void*)(g), \
    (__attribute__((address_space(3))) void*)(l), 16, 0, 0)

__device__ __forceinline__ u16 f2bf(float f){
  unsigned int u = __float_as_uint(f);
  u = (u + 0x7fffu + ((u >> 16) & 1u)) >> 16;
  return (u16)u;
}
__device__ __forceinline__ float bf2f(u16 s){
  return __uint_as_float(((unsigned int)s) << 16);
}
__device__ __forceinline__ void atomicMaxF(float* addr, float val){
  if(val >= 0.f) atomicMax((int*)addr, __float_as_int(val));
  else           atomicMin((unsigned int*)addr, __float_as_uint(val));
}
// gelu tanh-approx: z * sigmoid(2*(c1 z + c2 z^3))
__device__ __forceinline__ float fast_gelu(float z){
  float g2 = z*(1.5957691216f + 0.07135481628f*z*z);
  return z / (1.0f + __expf(-g2));
}

// ---------------- x = x + sinusoidal PE ----------------
__global__ void k_addpe(const float* __restrict__ x, float* __restrict__ xo){
  int idx = blockIdx.x*256 + threadIdx.x;
  int d = idx & (DMODEL-1);
  int n = (idx >> 9) & (SEQ-1);
  int j = d >> 1;
  float freq = expf((float)(2*j) * (-9.210340371976184f / (float)DMODEL));
  float ang = (float)n * freq;
  float pe = (d & 1) ? cosf(ang) : sinf(ang);
  xo[idx] = x[idx] + pe;
}

// ---------------- LayerNorm (512) -> bf16 ----------------
__global__ void k_ln(const float* __restrict__ x, const float* __restrict__ g,
                     const float* __restrict__ bv, u16* __restrict__ out){
  __shared__ float sred[8];
  int t = blockIdx.x, tid = threadIdx.x;
  const float2 v = ((const float2*)(x + (size_t)t*DMODEL))[tid];
  float s = v.x + v.y;
  #pragma unroll
  for(int o=32;o;o>>=1) s += __shfl_down(s,o);
  if((tid&63)==0) sred[tid>>6] = s;
  __syncthreads();
  if(tid==0) sred[4] = (sred[0]+sred[1]+sred[2]+sred[3]) * (1.0f/DMODEL);
  __syncthreads();
  float mu = sred[4];
  float dx = v.x - mu, dy = v.y - mu;
  float s2 = dx*dx + dy*dy;
  #pragma unroll
  for(int o=32;o;o>>=1) s2 += __shfl_down(s2,o);
  if((tid&63)==0) sred[tid>>6] = s2;
  __syncthreads();
  if(tid==0) sred[5] = rsqrtf((sred[0]+sred[1]+sred[2]+sred[3])*(1.0f/DMODEL) + LN_EPS);
  __syncthreads();
  float rs = sred[5];
  const float2 gg = ((const float2*)g)[tid];
  const float2 bb = ((const float2*)bv)[tid];
  ushort2 o2; o2.x = f2bf(dx*rs*gg.x + bb.x); o2.y = f2bf(dy*rs*gg.y + bb.y);
  ((ushort2*)(out + (size_t)t*DMODEL))[tid] = o2;
}

__global__ void k_pcvt(const float* __restrict__ p, u16* __restrict__ pb){
  int i = blockIdx.x*256 + threadIdx.x;
  pb[i] = f2bf(p[i]);
}

// ---------------- all weight transposes + ksum/kmax init in ONE dispatch ----------------
__global__ void k_wcvt_all(const float* __restrict__ wq, const float* __restrict__ wk,
                           const float* __restrict__ wv, const float* __restrict__ wo,
                           const float* __restrict__ w1, const float* __restrict__ w2,
                           u16* __restrict__ wqT, u16* __restrict__ wkT,
                           u16* __restrict__ wvT, u16* __restrict__ woT,
                           u16* __restrict__ w1T, u16* __restrict__ w2T,
                           float* __restrict__ ksum, float* __restrict__ kmax){
  int bid = blockIdx.x;
  if(bid >= 768){
    int i = (bid-768)*256 + threadIdx.x;
    ksum[i] = 0.f;
    if(i < BHN) kmax[i] = -INFINITY;
    return;
  }
  const float* src; u16* dst; int K, N, bx, by;
  if(bid < 256){
    int which = bid >> 6, sub = bid & 63;
    src = which==0 ? wq : which==1 ? wk : which==2 ? wv : wo;
    dst = which==0 ? wqT : which==1 ? wkT : which==2 ? wvT : woT;
    K = 512; N = 512; bx = sub & 7; by = sub >> 3;
  } else if(bid < 512){
    int sub = bid - 256; src = w1; dst = w1T; K = 512; N = 2048; bx = sub & 31; by = sub >> 5;
  } else {
    int sub = bid - 512; src = w2; dst = w2T; K = 2048; N = 512; bx = sub & 7; by = sub >> 3;
  }
  __shared__ float sm[64][65];
  int kt = by*64, nt = bx*64;
  int t = threadIdx.x, c = t & 63, r4 = t >> 6;
  #pragma unroll
  for(int i=0;i<16;i++){
    int kl = i*4 + r4;
    sm[kl][c] = src[(size_t)(kt+kl)*N + nt + c];
  }
  __syncthreads();
  #pragma unroll
  for(int i=0;i<16;i++){
    int nl = i*4 + r4;
    dst[(size_t)(nt+nl)*K + kt + c] = f2bf(sm[c][nl]);
  }
}

// ---------------- MFMA GEMM, 128x128, BK=32, depth-2, counted vmcnt, 128-reg cap ----------------
template<int EPI>
__global__ __launch_bounds__(256,4)
void k_mm(const u16* __restrict__ A, const u16* __restrict__ Bt,
          const float* __restrict__ bias, void* __restrict__ Cv,
          int Nc, int K){
  __shared__ u16 As[2][128*32];
  __shared__ u16 Bs[2][128*32];
  int tid = threadIdx.x;
  int w = tid >> 6, lane = tid & 63;
  int wr = w >> 1, wc = w & 1;
  int hi = lane >> 4, li = lane & 15;
  int row0 = blockIdx.y*128, col0 = blockIdx.x*128;
  int lr = lane >> 2;
  int cs = (lane & 3) ^ ((lane >> 3) & 3);
  const u16* gA = A  + (size_t)(row0 + w*16 + lr)*K + cs*8;
  const u16* gB = Bt + (size_t)(col0 + w*16 + lr)*K + cs*8;
  int rb = li*32 + ((hi ^ ((li>>1)&3))<<3);
  f32x4 acc[4][4] = {};

#define STAGE_MM(b,k0) { \
    GLOAD16(gA + (k0),                &As[b][(w*16)*32]);      \
    GLOAD16(gA + (size_t)64*K + (k0), &As[b][(64+w*16)*32]);   \
    GLOAD16(gB + (k0),                &Bs[b][(w*16)*32]);      \
    GLOAD16(gB + (size_t)64*K + (k0), &Bs[b][(64+w*16)*32]); }

  int nk = K >> 5;
  STAGE_MM(0, 0)
  STAGE_MM(1, 32)
  for(int t=0; t<nk; ++t){
    __builtin_amdgcn_sched_barrier(0);
    if(t+1 < nk){ asm volatile("s_waitcnt vmcnt(4)"); }
    else        { asm volatile("s_waitcnt vmcnt(0)"); }
    __builtin_amdgcn_s_barrier();
    __builtin_amdgcn_sched_barrier(0);
    const u16* pa = &As[t&1][0];
    const u16* pb = &Bs[t&1][0];
    bf16x8 bfr[4];
    #pragma unroll
    for(int q=0;q<4;q++) bfr[q] = *(const bf16x8*)&pb[rb + wc*2048 + q*512];
    __builtin_amdgcn_s_setprio(1);
    #pragma unroll
    for(int i2=0;i2<4;i2++){
      bf16x8 a = *(const bf16x8*)&pa[rb + wr*2048 + i2*512];
      #pragma unroll
      for(int j2=0;j2<4;j2++)
        acc[i2][j2] = MFMA16(a, bfr[j2], acc[i2][j2]);
    }
    __builtin_amdgcn_s_setprio(0);
    __builtin_amdgcn_sched_barrier(0);
    __builtin_amdgcn_s_barrier();
    __builtin_amdgcn_sched_barrier(0);
    if(t+2 < nk){ STAGE_MM(t&1, (size_t)(t+2)*32) }
  }
#undef STAGE_MM

  #pragma unroll
  for(int i2=0;i2<4;i2++){
    #pragma unroll
    for(int j2=0;j2<4;j2++){
      int col = col0 + wc*64 + j2*16 + li;
      float bcol = (EPI==2 || EPI==3) ? bias[col] : 0.f;
      if constexpr (EPI==4){
        int nb = row0 + wr*64 + i2*16 + hi*4;
        int b = nb >> 11, n = nb & (SEQ-1);
        int h = col >> 6, dh = col & 63;
        ushort4 pk;
        pk.x = f2bf(acc[i2][j2][0]); pk.y = f2bf(acc[i2][j2][1]);
        pk.z = f2bf(acc[i2][j2][2]); pk.w = f2bf(acc[i2][j2][3]);
        *(ushort4*)((u16*)Cv + (((size_t)(b*HNUM+h)*DHEAD + dh)*SEQ + n)) = pk;
      } else {
        #pragma unroll
        for(int r=0;r<4;r++){
          int row = row0 + wr*64 + i2*16 + hi*4 + r;
          float v = acc[i2][j2][r];
          if constexpr (EPI==1){
            int b = row >> 11, n = row & (SEQ-1);
            int h = col >> 6, dh = col & 63;
            ((u16*)Cv)[((size_t)(b*HNUM+h)*SEQ + n)*DHEAD + dh] = f2bf(v);
          } else if constexpr (EPI==2){
            ((float*)Cv)[(size_t)row*Nc + col] += v + bcol;
          } else {
            ((u16*)Cv)[(size_t)row*Nc + col] = f2bf(fast_gelu(v + bcol));
          }
        }
      }
    }
  }
}

// ---------------- MFMA GEMM, 256x128 tile, BK=64, 3-buffer phase-split ----------------
template<int EPI>
__global__ __launch_bounds__(512)
void k_mm8(const u16* __restrict__ A, const u16* __restrict__ Bt,
           const float* __restrict__ bias, void* __restrict__ Cv,
           int Nc, int K){
  __shared__ u16 Ab[3][256*64];
  __shared__ u16 Bb[3][128*64];
  int tid = threadIdx.x;
  int w = tid >> 6, lane = tid & 63;
  int wr = w >> 1, wc = w & 1;
  int hi = lane >> 4, li = lane & 15;
  int row0 = blockIdx.y*256, col0 = blockIdx.x*128;
  int lr = lane >> 3;
  int lc = (lane & 7) ^ lr;
  const u16* gA = A  + (size_t)(row0 + w*8 + lr)*K + lc*8;
  const u16* gB = Bt + (size_t)(col0 + w*8 + lr)*K + lc*8;
  f32x4 acc[4][4] = {};

#define STG8(buf,k0) { \
    GLOAD16(gA + (k0),                  &Ab[buf][w*512]);          \
    GLOAD16(gA + (size_t)64*K  + (k0),  &Ab[buf][4096  + w*512]);  \
    GLOAD16(gA + (size_t)128*K + (k0),  &Ab[buf][8192  + w*512]);  \
    GLOAD16(gA + (size_t)192*K + (k0),  &Ab[buf][12288 + w*512]);  \
    GLOAD16(gB + (k0),                  &Bb[buf][w*512]);          \
    GLOAD16(gB + (size_t)64*K  + (k0),  &Bb[buf][4096  + w*512]); }

  int nk = K >> 6;
  STG8(0, 0)
  STG8(1, 64)
  for(int t=0; t<nk; ++t){
    int buf = t % 3;
    int nbuf = (t+2) % 3;
    size_t nk0 = (size_t)(t+2)*64;
    __builtin_amdgcn_sched_barrier(0);
    if(t+1 < nk){ asm volatile("s_waitcnt vmcnt(6)"); }
    else        { asm volatile("s_waitcnt vmcnt(0)"); }
    __builtin_amdgcn_s_barrier();
    __builtin_amdgcn_sched_barrier(0);
    const u16* pa = &Ab[buf][0];
    const u16* pb = &Bb[buf][0];
    bf16x8 bfr[2][4], af[2][2];
    #pragma unroll
    for(int kk=0;kk<2;kk++){
      int kc = kk*4 + hi;
      #pragma unroll
      for(int j=0;j<4;j++){
        int bc = wc*64 + j*16 + li;
        bfr[kk][j] = *(const bf16x8*)&pb[bc*64 + ((kc ^ (bc&7))<<3)];
      }
      #pragma unroll
      for(int q=0;q<2;q++){
        int ar = wr*64 + q*16 + li;
        af[kk][q] = *(const bf16x8*)&pa[ar*64 + ((kc ^ (ar&7))<<3)];
      }
    }
    if(t+2 < nk){
      GLOAD16(gA + nk0,                  &Ab[nbuf][w*512]);
      GLOAD16(gA + (size_t)64*K  + nk0,  &Ab[nbuf][4096  + w*512]);
      GLOAD16(gA + (size_t)128*K + nk0,  &Ab[nbuf][8192  + w*512]);
    }
    __builtin_amdgcn_s_setprio(1);
    #pragma unroll
    for(int kk=0;kk<2;kk++)
      #pragma unroll
      for(int q=0;q<2;q++)
        #pragma unroll
        for(int j=0;j<4;j++)
          acc[q][j] = MFMA16(af[kk][q], bfr[kk][j], acc[q][j]);
    __builtin_amdgcn_s_setprio(0);
    __builtin_amdgcn_s_barrier();
    bf16x8 af2[2][2];
    #pragma unroll
    for(int kk=0;kk<2;kk++){
      int kc = kk*4 + hi;
      #pragma unroll
      for(int q=0;q<2;q++){
        int ar = wr*64 + (q+2)*16 + li;
        af2[kk][q] = *(const bf16x8*)&pa[ar*64 + ((kc ^ (ar&7))<<3)];
      }
    }
    if(t+2 < nk){
      GLOAD16(gA + (size_t)192*K + nk0,  &Ab[nbuf][12288 + w*512]);
      GLOAD16(gB + nk0,                  &Bb[nbuf][w*512]);
      GLOAD16(gB + (size_t)64*K  + nk0,  &Bb[nbuf][4096  + w*512]);
    }
    __builtin_amdgcn_s_setprio(1);
    #pragma unroll
    for(int kk=0;kk<2;kk++)
      #pragma unroll
      for(int q=0;q<2;q++)
        #pragma unroll
        for(int j=0;j<4;j++)
          acc[q+2][j] = MFMA16(af2[kk][q], bfr[kk][j], acc[q+2][j]);
    __builtin_amdgcn_s_setprio(0);
    __builtin_amdgcn_s_barrier();
  }
#undef STG8

  #pragma unroll
  for(int i2=0;i2<4;i2++){
    #pragma unroll
    for(int j2=0;j2<4;j2++){
      int col = col0 + wc*64 + j2*16 + li;
      float bcol = (EPI==2 || EPI==3) ? bias[col] : 0.f;
      if constexpr (EPI==4){
        int nb = row0 + wr*64 + i2*16 + hi*4;
        int b = nb >> 11, n = nb & (SEQ-1);
        int h = col >> 6, dh = col & 63;
        ushort4 pk;
        pk.x = f2bf(acc[i2][j2][0]); pk.y = f2bf(acc[i2][j2][1]);
        pk.z = f2bf(acc[i2][j2][2]); pk.w = f2bf(acc[i2][j2][3]);
        *(ushort4*)((u16*)Cv + (((size_t)(b*HNUM+h)*DHEAD + dh)*SEQ + n)) = pk;
      } else {
        #pragma unroll
        for(int r=0;r<4;r++){
          int row = row0 + wr*64 + i2*16 + hi*4 + r;
          float v = acc[i2][j2][r];
          if constexpr (EPI==1){
            int b = row >> 11, n = row & (SEQ-1);
            int h = col >> 6, dh = col & 63;
            ((u16*)Cv)[((size_t)(b*HNUM+h)*SEQ + n)*DHEAD + dh] = f2bf(v);
          } else if constexpr (EPI==2){
            ((float*)Cv)[(size_t)row*Nc + col] += v + bcol;
          } else {
            ((u16*)Cv)[(size_t)row*Nc + col] = f2bf(fast_gelu(v + bcol));
          }
        }
      }
    }
  }
}

// ---------------- K max pass: 128 rows/block, streaming acc ----------------
__global__ __launch_bounds__(256)
void k_kmax(const u16* __restrict__ xg, const u16* __restrict__ pjb,
            float* __restrict__ kmax){
  __shared__ u16 pj[256*64];
  __shared__ u16 xs[128*64];
  __shared__ float wred[4];
  int tid = threadIdx.x, w = tid >> 6, lane = tid & 63;
  int hi = lane >> 4, li = lane & 15;
  int r0 = blockIdx.x * 128;
  int bh = r0 >> 11;
  #pragma unroll
  for(int i=0;i<8;i++){
    int idx = i*256 + tid;
    int m = idx >> 3, c = idx & 7;
    bf16x8 v = *(const bf16x8*)(pjb + m*64 + c*8);
    *(bf16x8*)&pj[m*64 + ((c ^ (m&7))<<3)] = v;
  }
  #pragma unroll
  for(int i=0;i<4;i++){
    int idx = i*256 + tid;
    int m = idx >> 3, c = idx & 7;
    bf16x8 v = *(const bf16x8*)(xg + (size_t)(r0+m)*64 + c*8);
    *(bf16x8*)&xs[m*64 + ((c ^ (m&7))<<3)] = v;
  }
  __syncthreads();
  bf16x8 bfr[2][4];
  #pragma unroll
  for(int ks=0;ks<2;ks++){
    int kc = ks*4 + hi;
    #pragma unroll
    for(int t=0;t<4;t++){
      int bc = w*64 + t*16 + li;
      bfr[ks][t] = *(const bf16x8*)&pj[bc*64 + ((kc ^ (bc&7))<<3)];
    }
  }
  float mx = -1e30f;
  #pragma unroll
  for(int i8=0;i8<8;i8++){
    f32x4 acc[4] = {};
    #pragma unroll
    for(int ks=0;ks<2;ks++){
      int kc = ks*4 + hi;
      int ar = i8*16 + li;
      bf16x8 af = *(const bf16x8*)&xs[ar*64 + ((kc ^ (ar&7))<<3)];
      #pragma unroll
      for(int j2=0;j2<4;j2++)
        acc[j2] = MFMA16(af, bfr[ks][j2], acc[j2]);
    }
    #pragma unroll
    for(int j2=0;j2<4;j2++)
      #pragma unroll
      for(int r=0;r<4;r++) mx = fmaxf(mx, acc[j2][r]);
  }
  #pragma unroll
  for(int o=32;o;o>>=1) mx = fmaxf(mx, __shfl_xor(mx,o));
  if(lane==0) wred[w] = mx;
  __syncthreads();
  if(tid==0){
    float m2 = fmaxf(fmaxf(wred[0],wred[1]), fmaxf(wred[2],wred[3]));
    atomicMaxF(&kmax[bh], m2*DNRM);
  }
}

// ---------------- K feature pass: 128 rows/block, kp_t + ksum, register diag ----------------
__global__ __launch_bounds__(256)
void k_kfeat(const u16* __restrict__ xg, const u16* __restrict__ pjb,
             u16* __restrict__ outp, const float* __restrict__ kmax,
             float* __restrict__ ksum){
  __shared__ u16 pj[256*64];
  __shared__ u16 xs[128*64];
  __shared__ float dgs[128];
  int tid = threadIdx.x, w = tid >> 6, lane = tid & 63;
  int hi = lane >> 4, li = lane & 15;
  int r0 = blockIdx.x * 128;
  int bh = r0 >> 11;
  int nbase = r0 & (SEQ-1);
  #pragma unroll
  for(int i=0;i<8;i++){
    int idx = i*256 + tid;
    int m = idx >> 3, c = idx & 7;
    bf16x8 v = *(const bf16x8*)(pjb + m*64 + c*8);
    *(bf16x8*)&pj[m*64 + ((c ^ (m&7))<<3)] = v;
  }
  #pragma unroll
  for(int i=0;i<4;i++){
    int idx = i*256 + tid;
    int m = idx >> 3, c = idx & 7;
    bf16x8 v = *(const bf16x8*)(xg + (size_t)(r0+m)*64 + c*8);
    *(bf16x8*)&xs[m*64 + ((c ^ (m&7))<<3)] = v;
    float s = 0.f;
    #pragma unroll
    for(int j=0;j<8;j++){ float t = bf2f((u16)v[j]); s += t*t; }
    s += __shfl_xor(s,1); s += __shfl_xor(s,2); s += __shfl_xor(s,4);
    if((tid&7)==0) dgs[m] = 0.5f*DNRM*DNRM*s;
  }
  __syncthreads();
  bf16x8 bfr[2][4];
  #pragma unroll
  for(int ks=0;ks<2;ks++){
    int kc = ks*4 + hi;
    #pragma unroll
    for(int t=0;t<4;t++){
      int bc = w*64 + t*16 + li;
      bfr[ks][t] = *(const bf16x8*)&pj[bc*64 + ((kc ^ (bc&7))<<3)];
    }
  }
  float km = kmax[bh];
  float csum[4] = {0.f,0.f,0.f,0.f};
  #pragma unroll
  for(int i8=0;i8<8;i8++){
    f32x4 acc[4] = {};
    #pragma unroll
    for(int ks=0;ks<2;ks++){
      int kc = ks*4 + hi;
      int ar = i8*16 + li;
      bf16x8 af = *(const bf16x8*)&xs[ar*64 + ((kc ^ (ar&7))<<3)];
      #pragma unroll
      for(int j2=0;j2<4;j2++)
        acc[j2] = MFMA16(af, bfr[ks][j2], acc[j2]);
    }
    #pragma unroll
    for(int j2=0;j2<4;j2++){
      int col = w*64 + j2*16 + li;
      ushort4 pk;
      float cpart = 0.f;
      #pragma unroll
      for(int r=0;r<4;r++){
        int rl = i8*16 + hi*4 + r;
        float u = acc[j2][r]*DNRM;
        u16 eb = f2bf(SMF*(__expf(u - dgs[rl] - km) + EPSF));
        ((u16*)&pk)[r] = eb;
        cpart += bf2f(eb);
      }
      *(ushort4*)(outp + ((size_t)(bh*MFEAT + col)*SEQ + nbase + i8*16 + hi*4)) = pk;
      csum[j2] += cpart;
    }
  }
  #pragma unroll
  for(int j2=0;j2<4;j2++){
    float v = csum[j2];
    v += __shfl_xor(v,16); v += __shfl_xor(v,32);
    if(hi==0) atomicAdd(&ksum[bh*MFEAT + w*64 + j2*16 + li], v);
  }
}

// ---------------- fused Q-feature + PV, 512 threads / 64 rows per block ----------------
__global__ __launch_bounds__(512)
void k_feato(const u16* __restrict__ xg, const u16* __restrict__ pjb,
             const u16* __restrict__ ctxt, const float* __restrict__ ksum,
             u16* __restrict__ o){
  __shared__ u16 smA[16384];
  __shared__ u16 smX[4096];
  __shared__ u16 smQ[64*264];
  __shared__ float dgs[64];
  __shared__ float wred[2][4][32];
  __shared__ float wden[2][4][32];
  __shared__ float ksl[256];
  __shared__ float denl[64];
  int tid = threadIdx.x, w = tid >> 6, lane = tid & 63;
  int hi = lane >> 4, li = lane & 15;
  int g = w >> 2, wq = w & 3;
  int r0 = blockIdx.x * 64;
  int bh = r0 >> 11;
  int b = bh >> 3, h = bh & 7;
  #pragma unroll
  for(int i=0;i<4;i++){
    int idx = i*512 + tid;
    int m = idx >> 3, c = idx & 7;
    bf16x8 v = *(const bf16x8*)(pjb + m*64 + c*8);
    *(bf16x8*)&smA[m*64 + ((c ^ (m&7))<<3)] = v;
  }
  {
    int m = tid >> 3, c = tid & 7;
    bf16x8 v = *(const bf16x8*)(xg + (size_t)(r0+m)*64 + c*8);
    *(bf16x8*)&smX[m*64 + ((c ^ (m&7))<<3)] = v;
    float s = 0.f;
    #pragma unroll
    for(int j=0;j<8;j++){ float t = bf2f((u16)v[j]); s += t*t; }
    s += __shfl_xor(s,1); s += __shfl_xor(s,2); s += __shfl_xor(s,4);
    if((tid&7)==0) dgs[m] = 0.5f*DNRM*DNRM*s;
  }
  if(tid < 256) ksl[tid] = ksum[bh*MFEAT + tid];
  __syncthreads();
  f32x4 acc[2][4] = {};
  #pragma unroll
  for(int ks=0;ks<2;ks++){
    bf16x8 af[2], bfr[4];
    int kc = ks*4 + hi;
    #pragma unroll
    for(int t=0;t<2;t++){
      int ar = g*32 + t*16 + li;
      af[t] = *(const bf16x8*)&smX[ar*64 + ((kc ^ (ar&7))<<3)];
    }
    #pragma unroll
    for(int t=0;t<4;t++){
      int bc = wq*64 + t*16 + li;
      bfr[t] = *(const bf16x8*)&smA[bc*64 + ((kc ^ (bc&7))<<3)];
    }
    #pragma unroll
    for(int i2=0;i2<2;i2++)
      #pragma unroll
      for(int j2=0;j2<4;j2++)
        acc[i2][j2] = MFMA16(af[i2], bfr[j2], acc[i2][j2]);
  }
  __syncthreads();
  {
    int gch = (tid & 31) ^ ((tid >> 5) & 7);
    const u16* gCl = ctxt + (size_t)bh*DHEAD*MFEAT + (size_t)(tid>>5)*MFEAT + gch*8;
    #pragma unroll
    for(int i=0;i<4;i++)
      GLOAD16(gCl + (size_t)i*16*MFEAT, &smA[i*4096 + w*512]);
  }
  #pragma unroll
  for(int i2=0;i2<2;i2++){
    #pragma unroll
    for(int r=0;r<4;r++){
      float v = fmaxf(fmaxf(acc[i2][0][r],acc[i2][1][r]), fmaxf(acc[i2][2][r],acc[i2][3][r]));
      v = fmaxf(v, __shfl_xor(v,1)); v = fmaxf(v, __shfl_xor(v,2));
      v = fmaxf(v, __shfl_xor(v,4)); v = fmaxf(v, __shfl_xor(v,8));
      if(li==0) wred[g][wq][i2*16 + hi*4 + r] = v;
    }
  }
  __builtin_amdgcn_sched_barrier(0);
  asm volatile("s_waitcnt lgkmcnt(0)");
  __builtin_amdgcn_s_barrier();
  __builtin_amdgcn_sched_barrier(0);
  #pragma unroll
  for(int i2=0;i2<2;i2++){
    #pragma unroll
    for(int r=0;r<4;r++){
      int rl = i2*16 + hi*4 + r;
      int row = g*32 + rl;
      float rm = fmaxf(fmaxf(wred[g][0][rl],wred[g][1][rl]),
                       fmaxf(wred[g][2][rl],wred[g][3][rl]));
      float dsum = 0.f;
      #pragma unroll
      for(int j2=0;j2<4;j2++){
        int col = wq*64 + j2*16 + li;
        float u = acc[i2][j2][r]*DNRM;
        u16 eb = f2bf(SMF*(__expf(u - dgs[row] - rm) + EPSF));
        smQ[row*264 + col] = eb;
        dsum += bf2f(eb)*ksl[col];
      }
      dsum += __shfl_xor(dsum,1); dsum += __shfl_xor(dsum,2);
      dsum += __shfl_xor(dsum,4); dsum += __shfl_xor(dsum,8);
      if(li==0) wden[g][wq][rl] = dsum;
    }
  }
  __builtin_amdgcn_sched_barrier(0);
  asm volatile("s_waitcnt vmcnt(0) lgkmcnt(0)");
  __builtin_amdgcn_s_barrier();
  __builtin_amdgcn_sched_barrier(0);
  if(tid < 64){
    int gg = tid >> 5, rr = tid & 31;
    denl[tid] = wden[gg][0][rr]+wden[gg][1][rr]+wden[gg][2][rr]+wden[gg][3][rr];
  }
  int d4 = w >> 1, g2 = w & 1;
  f32x4 acc2[2] = {};
  #pragma unroll
  for(int s=0;s<8;s++){
    int kc = s*4 + hi;
    int bc = d4*16 + li;
    bf16x8 bf = *(const bf16x8*)&smA[bc*256 + ((kc ^ (bc&7))<<3)];
    #pragma unroll
    for(int t=0;t<2;t++){
      int ar = g2*32 + t*16 + li;
      bf16x8 aa = *(const bf16x8*)&smQ[ar*264 + kc*8];
      acc2[t] = MFMA16(aa, bf, acc2[t]);
    }
  }
  __syncthreads();
  int nbase = r0 & (SEQ-1);
  #pragma unroll
  for(int t=0;t<2;t++){
    #pragma unroll
    for(int r=0;r<4;r++){
      int nl = g2*32 + t*16 + hi*4 + r;
      float di = 1.0f/denl[nl];
      o[((size_t)b*SEQ + nbase + nl)*DMODEL + h*DHEAD + d4*16 + li] = f2bf(acc2[t][r]*di);
    }
  }
}

// ---------------- ctx_t: m-tile 32, grid (8,BHN), 2 blocks/CU, depth-2 pipeline ----------------
__global__ __launch_bounds__(256)
void k_ctx(const u16* __restrict__ vt, const u16* __restrict__ kpt,
           u16* __restrict__ ctxt){
  __shared__ u16 As[2][64*64];
  __shared__ u16 Bs[2][32*64];
  int tid = threadIdx.x, w = tid >> 6, lane = tid & 63;
  int wr = w >> 1, wc = w & 1;
  int hi = lane >> 4, li = lane & 15;
  int bh = blockIdx.y, mb = blockIdx.x*32;
  int lr = lane >> 3;
  int lc = (lane & 7) ^ lr;
  const u16* gA = vt  + (size_t)bh*DHEAD*SEQ + (size_t)(w*8 + lr)*SEQ + lc*8;
  const u16* gB = kpt + ((size_t)bh*MFEAT + mb + w*8 + lr)*SEQ + lc*8;
  f32x4 acc[2][1] = {};
#define STAGE_CTX(b,k0) { \
    GLOAD16(gA + (k0),                  &As[b][(w*8)*64]);      \
    GLOAD16(gA + (size_t)32*SEQ + (k0), &As[b][(32+w*8)*64]);   \
    GLOAD16(gB + (k0),                  &Bs[b][(w*8)*64]); }
  int nk = SEQ/64;
  STAGE_CTX(0, 0)
  STAGE_CTX(1, 64)
  for(int t=0; t<nk; ++t){
    __builtin_amdgcn_sched_barrier(0);
    if(t+1 < nk){ asm volatile("s_waitcnt vmcnt(3)"); }
    else        { asm volatile("s_waitcnt vmcnt(0)"); }
    __builtin_amdgcn_s_barrier();
    __builtin_amdgcn_sched_barrier(0);
    const u16* pa = &As[t&1][0];
    const u16* pb = &Bs[t&1][0];
    #pragma unroll
    for(int ks=0;ks<2;ks++){
      bf16x8 af[2], bfr;
      int kc = ks*4 + hi;
      #pragma unroll
      for(int q=0;q<2;q++){
        int ar = wr*32 + q*16 + li;
        af[q] = *(const bf16x8*)&pa[ar*64 + ((kc ^ (ar&7))<<3)];
      }
      {
        int bc = wc*16 + li;
        bfr = *(const bf16x8*)&pb[bc*64 + ((kc ^ (bc&7))<<3)];
      }
      __builtin_amdgcn_s_setprio(1);
      #pragma unroll
      for(int i2=0;i2<2;i2++)
        acc[i2][0] = MFMA16(af[i2], bfr, acc[i2][0]);
      __builtin_amdgcn_s_setprio(0);
    }
    __builtin_amdgcn_sched_barrier(0);
    __builtin_amdgcn_s_barrier();
    __builtin_amdgcn_sched_barrier(0);
    if(t+2 < nk){ STAGE_CTX(t&1, (size_t)(t+2)*64) }
  }
#undef STAGE_CTX
  #pragma unroll
  for(int i2=0;i2<2;i2++){
    int m = mb + wc*16 + li;
    #pragma unroll
    for(int r=0;r<4;r++){
      int dh = wr*32 + i2*16 + hi*4 + r;
      ctxt[((size_t)bh*DHEAD + dh)*MFEAT + m] = f2bf(acc[i2][0][r]);
    }
  }
}

extern "C" void kernel_launch(void* const* d_in, const int* in_sizes, int n_in,
                              void* d_out, int out_size, void* d_ws, size_t ws_size,
                              hipStream_t stream){
  (void)in_sizes; (void)n_in; (void)out_size; (void)ws_size;
  const float* x    = (const float*)d_in[0];
  const float* proj = (const float*)d_in[1];
  const float* ln1g = (const float*)d_in[2];
  const float* ln1b = (const float*)d_in[3];
  const float* wq   = (const float*)d_in[4];
  const float* wk   = (const float*)d_in[5];
  const float* wv   = (const float*)d_in[6];
  const float* wo   = (const float*)d_in[7];
  const float* bo   = (const float*)d_in[8];
  const float* ln2g = (const float*)d_in[9];
  const float* ln2b = (const float*)d_in[10];
  const float* w1   = (const float*)d_in[11];
  const float* b1   = (const float*)d_in[12];
  const float* w2   = (const float*)d_in[13];
  const float* b2   = (const float*)d_in[14];
  float* xo = (float*)d_out;

  // workspace ~110 MB
  char* ws = (char*)d_ws;
  u16* bufH  = (u16*)ws;  ws += (size_t)TOK*DMODEL*2;
  u16* bufA  = (u16*)ws;  ws += (size_t)TOK*DMODEL*2;
  u16* featb = (u16*)ws;  ws += (size_t)BHN*SEQ*MFEAT*2;
  u16* ctxt  = (u16*)ws;  ws += (size_t)BHN*DHEAD*MFEAT*2;
  u16* wT    = (u16*)ws;  ws += (size_t)3*1048576*2;
  u16* pjb   = (u16*)ws;  ws += (size_t)LNUM*MFEAT*DHEAD*2;
  float* ksum= (float*)ws; ws += (size_t)BHN*MFEAT*4;
  float* kmax= (float*)ws; ws += 256;

  u16* wqT = wT;
  u16* wkT = wT +  262144;
  u16* wvT = wT +  524288;
  u16* woT = wT +  786432;
  u16* w1T = wT + 1048576;
  u16* w2T = wT + 2097152;

  k_addpe<<<(TOK*DMODEL)/256, 256, 0, stream>>>(x, xo);
  k_pcvt<<<(LNUM*MFEAT*DHEAD)/256, 256, 0, stream>>>(proj, pjb);

  for(int l=0; l<LNUM; l++){
    const u16* pj_l = pjb + (size_t)l*MFEAT*DHEAD;
    k_wcvt_all<<<832, 256, 0, stream>>>(wq + (size_t)l*262144, wk + (size_t)l*262144,
                                        wv + (size_t)l*262144, wo + (size_t)l*262144,
                                        w1 + (size_t)l*1048576, w2 + (size_t)l*1048576,
                                        wqT, wkT, wvT, woT, w1T, w2T, ksum, kmax);
    k_ln<<<TOK, 256, 0, stream>>>(xo, ln1g + l*DMODEL, ln1b + l*DMODEL, bufH);
    // K path: k -> kmax -> kp_t (+ksum atomics)
    k_mm8<1><<<dim3(4,64), 512, 0, stream>>>(bufH, wkT, nullptr, bufA, DMODEL, DMODEL);
    k_kmax<<<(BHN*SEQ)/128, 256, 0, stream>>>(bufA, pj_l, kmax);
    k_kfeat<<<(BHN*SEQ)/128, 256, 0, stream>>>(bufA, pj_l, featb, kmax, ksum);
    // V path: v_t -> ctx_t
    k_mm8<4><<<dim3(4,64), 512, 0, stream>>>(bufH, wvT, nullptr, bufA, DMODEL, DMODEL);
    k_ctx<<<dim3(8,BHN), 256, 0, stream>>>(bufA, featb, ctxt);
    // Q path fused: q -> qp (LDS) -> o  -> wo-GEMM (residual add)
    k_mm8<1><<<dim3(4,64), 512, 0, stream>>>(bufH, wqT, nullptr, bufA, DMODEL, DMODEL);
    k_feato<<<(BHN*SEQ)/64, 512, 0, stream>>>(bufA, pj_l, ctxt, ksum, bufH);
    k_mm8<2><<<dim3(4,64), 512, 0, stream>>>(bufH, woT, bo + l*DMODEL, xo, DMODEL, DMODEL);
    // FFN: w1 on k_mm (1024-block TLP regime); w2 on k_mm8 (256-block fill regime)
    k_ln<<<TOK, 256, 0, stream>>>(xo, ln2g + l*DMODEL, ln2b + l*DMODEL, bufA);
    k_mm<3><<<dim3(16,128), 256, 0, stream>>>(bufA, w1T, b1 + l*DFF, featb, DFF, DMODEL);
    k_mm8<2><<<dim3(4,64), 512, 0, stream>>>(featb, w2T, b2 + l*DMODEL, xo, DMODEL, DFF);
  }
}